// Round 1
// baseline (47306.778 us; speedup 1.0000x reference)
//
#include <hip/hip_runtime.h>
#include <cstdint>
#include <cstddef>

// ---------------------------------------------------------------------------
// Tacotron2-style decoder, persistent-kernel implementation.
// 256 blocks x 256 threads, custom device-scope grid barrier (all blocks are
// co-resident: 42KB LDS, <=128 VGPR target, 256 blocks on 256 CUs).
// ---------------------------------------------------------------------------

#define NB 256
#define NT 256

#define Bz   8
#define TE   512
#define DINz 512
#define TDz  150
#define ODz  80
#define DRz  1024
#define PREz 256
#define ATz  128
#define LOCz 32
#define KFz  31

// workspace offsets (in floats)
#define OF_PM   0            // proc_mem [8][512][128]
#define OF_F    524288       // F = W_loc @ filters  [128][31]
#define OF_P    528256       // prenet outs [150][8][256]
#define OF_Q    835456       // q [128][8]
#define OF_U    836480       // unnormalized softmax u [8][512]
#define OF_CUM  840576       // att_cum [8][512]
#define OF_ATTC 844672       // unnormalized att_c [2][8][512]
#define OF_S    852864       // S [2][8]
#define OF_INVS 852880       // 1/S [2][8]
#define OF_H0   852896       // h0 [8][1024]
#define OF_C0   861088
#define OF_H1   869280
#define OF_C1   877472
#define OF_GH0  885664       // gh0 [4096][8]
#define OF_GH1  918432       // gh1 [4096][8]
#define OF_BAR  951200       // barrier: 2 ints
#define WS_FLOATS 951232

// shared memory layout (floats)
#define SM_WT 0       // gemm W tile 32x256
#define SM_XT 8192    // gemm X tile 8x256
#define SM_G  8448    // gate exchange (256)
#define SM_TOT 10496

__device__ __forceinline__ float fsig_(float x){ return 1.f/(1.f + __expf(-x)); }
__device__ __forceinline__ float ftanh_(float x){
  x = fminf(10.f, fmaxf(-10.f, x));
  float e = __expf(2.f*x);
  return (e - 1.f) / (e + 1.f);
}

__device__ __forceinline__ void grid_barrier(int* bar){
  __syncthreads();
  if (threadIdx.x == 0){
    __threadfence();   // agent-scope release of this block's prior writes
    int g = __hip_atomic_load(&bar[1], __ATOMIC_ACQUIRE, __HIP_MEMORY_SCOPE_AGENT);
    int old = __hip_atomic_fetch_add(&bar[0], 1, __ATOMIC_ACQ_REL, __HIP_MEMORY_SCOPE_AGENT);
    if (old == NB-1){
      __hip_atomic_store(&bar[0], 0,   __ATOMIC_RELAXED, __HIP_MEMORY_SCOPE_AGENT);
      __hip_atomic_store(&bar[1], g+1, __ATOMIC_RELEASE, __HIP_MEMORY_SCOPE_AGENT);
    } else {
      while (__hip_atomic_load(&bar[1], __ATOMIC_ACQUIRE, __HIP_MEMORY_SCOPE_AGENT) == g)
        __builtin_amdgcn_s_sleep(2);
    }
  }
  __syncthreads();
}

// GEMM: out[row(0..31)][b(0..7)] = sum_k W[maprow(row)][k] * X[b][k]
// 256 threads: thread = pos(0..7)*32 + s(0..31); thread owns rows pos*4..+3,
// all 8 b, K-slice {s+32j}; final cross-slice reduction through LDS.
// Returns per-thread value for (row32 = tid>>3, b = tid&7).
__device__ float gemm32x8(
    float* sm,
    const float* __restrict__ W0, const float* __restrict__ W1, int rowSplit,
    int gatemap, int u0, int rowbase, int K, int nch,
    int xmode, const float* __restrict__ xsrc,
    const float* __restrict__ attc_cur, const float* __restrict__ invS_cur,
    const float* __restrict__ Pt)
{
  const int tid = threadIdx.x;
  const int s = tid & 31, pos = tid >> 5;
  float acc[4][8];
  #pragma unroll
  for (int i=0;i<4;++i){
    #pragma unroll
    for (int b=0;b<8;++b) acc[i][b] = 0.f;
  }
  __syncthreads();   // protect smem reuse within a phase
  for (int ch=0; ch<nch; ++ch){
    const int c0 = ch << 8;
    // stage W tile (32 x 256), fully coalesced float4
    #pragma unroll
    for (int it=0; it<8; ++it){
      int idx4 = tid + (it<<8);
      int r   = idx4 >> 6;
      int col = (idx4 & 63) << 2;
      int grow = gatemap ? (((r>>3)<<10) + u0 + (r&7)) : (rowbase + r);
      const float* Wr = (grow < rowSplit) ? (W0 + (size_t)grow*K)
                                          : (W1 + (size_t)(grow-rowSplit)*K);
      float4 v = *reinterpret_cast<const float4*>(Wr + c0 + col);
      *reinterpret_cast<float4*>(&sm[SM_WT + (r<<8) + col]) = v;
    }
    // stage X tile (8 x 256)
    #pragma unroll
    for (int it=0; it<2; ++it){
      int idx4 = tid + (it<<8);
      int b   = idx4 >> 6;
      int col = (idx4 & 63) << 2;
      float4 v;
      if (xmode == 0){
        v = *reinterpret_cast<const float4*>(xsrc + (size_t)b*K + c0 + col);
      } else if (ch < 2){
        v = *reinterpret_cast<const float4*>(attc_cur + (b<<9) + c0 + col);
        float sc = invS_cur[b];
        v.x*=sc; v.y*=sc; v.z*=sc; v.w*=sc;
      } else {
        v = *reinterpret_cast<const float4*>(Pt + (b<<8) + col);
      }
      *reinterpret_cast<float4*>(&sm[SM_XT + (b<<8) + col]) = v;
    }
    __syncthreads();
    // compute: stride-1-per-lane LDS (conflict-free; pos-pair aliasing is 2-way=free)
    #pragma unroll
    for (int j=0;j<8;++j){
      const int k = s + (j<<5);
      float xb[8];
      #pragma unroll
      for (int b=0;b<8;++b) xb[b] = sm[SM_XT + (b<<8) + k];
      #pragma unroll
      for (int i=0;i<4;++i){
        float w = sm[SM_WT + (((pos<<2)+i)<<8) + k];
        #pragma unroll
        for (int b=0;b<8;++b) acc[i][b] = fmaf(w, xb[b], acc[i][b]);
      }
    }
    __syncthreads();
  }
  // cross-slice reduction (pad 33 -> conflict-free)
  #pragma unroll
  for (int i=0;i<4;++i){
    #pragma unroll
    for (int b=0;b<8;++b){
      int rb = (((pos<<2)+i)<<3) + b;
      sm[rb*33 + s] = acc[i][b];
    }
  }
  __syncthreads();
  float sum = 0.f;
  #pragma unroll
  for (int s2=0; s2<32; ++s2) sum += sm[tid*33 + s2];
  return sum;
}

// LSTM gate combine + zoneout (eval form). dot is for (row32=tid>>3,b=tid&7),
// row32 = gate*8 + unit_local, grow = gate*1024 + u0 + unit_local.
__device__ void lstm_epilogue(float* sm, float dot,
                              const float* __restrict__ bias,
                              const float* __restrict__ gh,
                              float* __restrict__ h, float* __restrict__ c, int u0)
{
  const int tid = threadIdx.x;
  const int row32 = tid >> 3, b = tid & 7;
  const int gate = row32 >> 3, ul = row32 & 7;
  const int grow = (gate<<10) + u0 + ul;
  sm[SM_G + tid] = dot + bias[grow] + gh[(grow<<3) + b];
  __syncthreads();
  if (tid < 64){
    float gi = sm[SM_G + tid];        // i
    float gf = sm[SM_G + 64 + tid];   // f
    float gg = sm[SM_G + 128 + tid];  // g (cell)
    float go = sm[SM_G + 192 + tid];  // o
    int ul2 = tid >> 3, b2 = tid & 7;
    int hi = (b2<<10) + u0 + ul2;
    float co = c[hi], ho = h[hi];
    float cn = fsig_(gf)*co + fsig_(gi)*ftanh_(gg);
    float hn = fsig_(go)*ftanh_(cn);
    c[hi] = 0.9f*cn + 0.1f*co;
    h[hi] = 0.9f*hn + 0.1f*ho;
  }
}

// one row of [h1, att_c] @ [feat_W;stop_W]^T  (rr = b*81 + r; r==80 -> stop)
__device__ void outstop_row(int rr, int tp, int par,
    const float* __restrict__ feat_W, const float* __restrict__ stop_W,
    const float* __restrict__ stop_b, const float* __restrict__ h1,
    const float* __restrict__ attc, const float* __restrict__ invS,
    float* __restrict__ d_out)
{
  int b = rr / 81, r = rr - 81*b;
  const float4* Wr  = reinterpret_cast<const float4*>((r < 80) ? (feat_W + (size_t)r*1536) : stop_W);
  const float4* h1b = reinterpret_cast<const float4*>(h1 + (b<<10));
  const float4* ac  = reinterpret_cast<const float4*>(attc + (par<<12) + (b<<9));
  float acc = 0.f, acc2 = 0.f;
  for (int j=0;j<256;++j){
    float4 w = Wr[j], x = h1b[j];
    acc = fmaf(w.x,x.x, fmaf(w.y,x.y, fmaf(w.z,x.z, fmaf(w.w,x.w, acc))));
  }
  for (int j=0;j<128;++j){
    float4 w = Wr[256+j], x = ac[j];
    acc2 = fmaf(w.x,x.x, fmaf(w.y,x.y, fmaf(w.z,x.z, fmaf(w.w,x.w, acc2))));
  }
  float val = acc + acc2 * invS[(par<<3)+b];
  if (r < 80) d_out[((size_t)b*TDz + tp)*ODz + r] = val;
  else        d_out[96000 + (size_t)b*TDz + tp] = val + stop_b[0];
}

extern "C" __global__ void dec_kernel(
  const float* __restrict__ memory, const int* __restrict__ mlen, const float* __restrict__ targets,
  const float* __restrict__ W_mem, const float* __restrict__ W_q, const float* __restrict__ W_loc,
  const float* __restrict__ loc_f, const float* __restrict__ attn_v, const float* __restrict__ attn_b,
  const float* __restrict__ pre_W1, const float* __restrict__ pre_b1,
  const float* __restrict__ pre_W2, const float* __restrict__ pre_b2,
  const float* __restrict__ Wi0, const float* __restrict__ Wh0, const float* __restrict__ bl0,
  const float* __restrict__ Wi1, const float* __restrict__ Wh1, const float* __restrict__ bl1,
  const float* __restrict__ feat_W, const float* __restrict__ stop_W, const float* __restrict__ stop_b,
  float* __restrict__ d_out, float* __restrict__ ws)
{
  __shared__ float sm[SM_TOT];
  const int blk = blockIdx.x, tid = threadIdx.x;

  float* pm   = ws + OF_PM;
  float* Fw   = ws + OF_F;
  float* Pw   = ws + OF_P;
  float* qw   = ws + OF_Q;
  float* uw   = ws + OF_U;
  float* cum  = ws + OF_CUM;
  float* attc = ws + OF_ATTC;
  float* Sw   = ws + OF_S;
  float* iSw  = ws + OF_INVS;
  float* h0 = ws + OF_H0; float* c0 = ws + OF_C0;
  float* h1 = ws + OF_H1; float* c1 = ws + OF_C1;
  float* gh0 = ws + OF_GH0; float* gh1 = ws + OF_GH1;
  int* bar = (int*)(ws + OF_BAR);

  // ------------------------- INIT (every launch) ---------------------------
  {
    const int gstride = NB*NT;
    int gid = blk*NT + tid;
    for (int i = gid; i < 1024;  i += gstride) qw[i]  = 0.f;
    for (int i = gid; i < 4096;  i += gstride) cum[i] = 0.f;
    for (int i = gid; i < 16;    i += gstride) Sw[i]  = 0.f;
    for (int i = gid; i < 65536; i += gstride) h0[i]  = 0.f;  // h0,c0,h1,c1,gh0 contiguous

    // F[a][k] = sum_c W_loc[a][c] * filters[c][0][k]
    if (gid < ATz*KFz){
      int a = gid / KFz, k = gid - a*KFz;
      float s2 = 0.f;
      for (int cc=0; cc<LOCz; ++cc) s2 = fmaf(W_loc[a*LOCz+cc], loc_f[cc*KFz+k], s2);
      Fw[gid] = s2;
    }

    // proc_mem[b][i][a] = memory[b,i,:] . W_mem[a,:]
    {
      int b = blk >> 5, i0 = (blk & 31) << 4;
      for (int idx = tid; idx < 16*DINz; idx += NT)
        sm[idx] = memory[(size_t)((b<<9) + i0 + (idx>>9))*DINz + (idx & 511)];
      __syncthreads();
      int il = tid >> 4, ag = tid & 15;
      const float* mrow = &sm[il<<9];
      for (int jj=0;jj<8;++jj){
        int a = (jj<<4) + ag;
        const float* wr = W_mem + (size_t)a*DINz;
        float acc = 0.f;
        for (int d=0; d<DINz; d+=4){
          acc = fmaf(mrow[d  ], wr[d  ], acc);
          acc = fmaf(mrow[d+1], wr[d+1], acc);
          acc = fmaf(mrow[d+2], wr[d+2], acc);
          acc = fmaf(mrow[d+3], wr[d+3], acc);
        }
        pm[((size_t)((b<<9)+i0+il)<<7) + a] = acc;
      }
      __syncthreads();
    }

    // prenet for all (t,b): teacher-forced, independent of the recurrence
    for (int pair = blk; pair < TDz*Bz; pair += NB){
      int tt = pair >> 3, b = pair & 7;
      if (tid < ODz) sm[tid] = (tt==0) ? 0.f : targets[((size_t)b*TDz + (tt-1))*ODz + tid];
      __syncthreads();
      float a1 = pre_b1[tid];
      for (int k=0;k<ODz;++k) a1 = fmaf(pre_W1[tid*ODz+k], sm[k], a1);
      a1 = fmaxf(a1, 0.f);
      sm[128 + tid] = a1;
      __syncthreads();
      float a2 = pre_b2[tid];
      for (int k=0;k<PREz;++k) a2 = fmaf(pre_W2[(tid<<8)+k], sm[128+k], a2);
      Pw[((size_t)pair<<8) + tid] = fmaxf(a2, 0.f);
      __syncthreads();
    }
  }
  grid_barrier(bar);

  // ------------------------------ MAIN LOOP --------------------------------
  for (int t = 0; t < TDz; ++t){
    const int cur = t & 1, prv = cur ^ 1;

    // ---- P1: e -> u (unnormalized softmax; |e|<=~2 so exp is safe) --------
    {
      int b = blk >> 5, i0 = (blk & 31) << 4;
      for (int idx = tid; idx < ATz*KFz; idx += NT) sm[idx] = Fw[idx];
      if (tid < 46){
        int gi2 = i0 - 15 + tid;
        sm[3968+tid] = (gi2 >= 0 && gi2 < TE) ? cum[(b<<9)+gi2] : 0.f;
      }
      if (tid < ATz){
        sm[4032+tid] = qw[(tid<<3) + b];   // q[a][b]
        sm[4160+tid] = attn_v[tid];
        sm[4288+tid] = attn_b[tid];
      }
      __syncthreads();
      int il = tid >> 4, ag = tid & 15;
      float cumr[KFz];
      #pragma unroll
      for (int k=0;k<KFz;++k) cumr[k] = sm[3968 + il + k];
      const float* pmrow = pm + ((size_t)((b<<9) + i0 + il) << 7);
      float part = 0.f;
      #pragma unroll
      for (int jj=0;jj<8;++jj){
        int a = (jj<<4) + ag;
        const float* fb = &sm[a*KFz];
        float conv = 0.f;
        #pragma unroll
        for (int k=0;k<KFz;++k) conv = fmaf(fb[k], cumr[k], conv);
        float arg = pmrow[a] + sm[4032+a] + sm[4288+a] + conv;
        part = fmaf(sm[4160+a], ftanh_(arg), part);
      }
      part += __shfl_down(part, 8, 16);
      part += __shfl_down(part, 4, 16);
      part += __shfl_down(part, 2, 16);
      part += __shfl_down(part, 1, 16);
      if (ag == 0){
        int gi2 = i0 + il;
        float uu = (gi2 < mlen[b]) ? __expf(part) : 0.f;
        uw[(b<<9)+gi2] = uu;
        sm[4416+il] = uu;
      }
      __syncthreads();
      if (tid == 0){
        float s2 = 0.f;
        for (int k=0;k<16;++k) s2 += sm[4416+k];
        atomicAdd(&Sw[(cur<<3)+b], s2);
      }
    }
    grid_barrier(bar);

    // ---- P2: att_w/att_cum (8) | att_c unnorm (64) | gh1 = h1@Wh1^T (128) -
    if (blk < 8){
      int b = blk;
      float inv = 1.f / Sw[(cur<<3)+b];
      if (tid == 0) iSw[(cur<<3)+b] = inv;
      for (int i = tid; i < TE; i += NT){
        float w = uw[(b<<9)+i] * inv;
        d_out[97200 + ((size_t)b*TDz + t)*TE + i] = w;
        cum[(b<<9)+i] += w;
      }
    } else if (blk < 72){
      int idx = blk - 8, b = idx >> 3, d0 = (idx & 7) << 6;
      for (int i = tid; i < TE; i += NT) sm[i] = uw[(b<<9)+i];
      __syncthreads();
      int dd = tid & 63, is = tid >> 6;
      float acc = 0.f;
      for (int i = is; i < TE; i += 4)
        acc = fmaf(sm[i], memory[(size_t)((b<<9)+i)*DINz + d0 + dd], acc);
      sm[512 + dd*5 + is] = acc;
      __syncthreads();
      if (tid < 64){
        float s2 = 0.f;
        #pragma unroll
        for (int k=0;k<4;++k) s2 += sm[512 + tid*5 + k];
        attc[(cur<<12) + (b<<9) + d0 + tid] = s2;
      }
    } else if (blk < 200){
      int tile = blk - 72;
      float dot = gemm32x8(sm, Wh1, Wh1, 1<<30, 0, 0, tile<<5, DRz, 4,
                           0, h1, nullptr, nullptr, nullptr);
      gh1[(tile<<8) + tid] = dot;
    }
    grid_barrier(bar);

    // ---- P3: LSTM0 finalize (128) | zero S[next] | out/stop for t-1 -------
    if (blk < 128){
      float dot = gemm32x8(sm, Wi0, Wi0, 1<<30, 1, blk<<3, 0, 768, 3,
                           1, nullptr, attc + (cur<<12), iSw + (cur<<3),
                           Pw + ((size_t)t<<11));
      lstm_epilogue(sm, dot, bl0, gh0, h0, c0, blk<<3);
    } else if (blk == 128){
      if (tid < 8) Sw[(prv<<3)+tid] = 0.f;
    } else {
      if (t > 0 && tid < 6){
        int rr = (blk - 129)*6 + tid;
        if (rr < 648) outstop_row(rr, t-1, prv, feat_W, stop_W, stop_b, h1, attc, iSw, d_out);
      }
    }
    grid_barrier(bar);

    // ---- P4: LSTM1 finalize (128) | gh0_{t+1} & q_{t+1} producer (128) ----
    if (blk < 128){
      float dot = gemm32x8(sm, Wi1, Wi1, 1<<30, 1, blk<<3, 0, DRz, 4,
                           0, h0, nullptr, nullptr, nullptr);
      lstm_epilogue(sm, dot, bl1, gh1, h1, c1, blk<<3);
    } else {
      for (int tile = blk - 128; tile < 132; tile += 128){
        float dot = gemm32x8(sm, Wh0, W_q, 4096, 0, 0, tile<<5, DRz, 4,
                             0, h0, nullptr, nullptr, nullptr);
        if (tile < 128) gh0[(tile<<8) + tid] = dot;
        else            qw[((tile-128)<<8) + tid] = dot;
      }
    }
    grid_barrier(bar);
  }

  // final out/stop for t = 149 (last P4 barrier made h1/attc/invS visible)
  if (blk >= 129 && tid < 6){
    int rr = (blk - 129)*6 + tid;
    if (rr < 648) outstop_row(rr, TDz-1, 1, feat_W, stop_W, stop_b, h1, attc, iSw, d_out);
  }
}

extern "C" void kernel_launch(void* const* d_in, const int* in_sizes, int n_in,
                              void* d_out, int out_size, void* d_ws, size_t ws_size,
                              hipStream_t stream)
{
  (void)in_sizes; (void)n_in; (void)out_size; (void)ws_size;
  // zero the barrier counters (ws is re-poisoned before every timed launch)
  hipMemsetAsync((char*)d_ws + (size_t)OF_BAR*4, 0, 16, stream);
  dec_kernel<<<dim3(NB), dim3(NT), 0, stream>>>(
    (const float*)d_in[0],  (const int*)d_in[1],   (const float*)d_in[2],
    (const float*)d_in[3],  (const float*)d_in[4],  (const float*)d_in[5],
    (const float*)d_in[6],  (const float*)d_in[7],  (const float*)d_in[8],
    (const float*)d_in[9],  (const float*)d_in[10], (const float*)d_in[11], (const float*)d_in[12],
    (const float*)d_in[13], (const float*)d_in[14], (const float*)d_in[15],
    (const float*)d_in[16], (const float*)d_in[17], (const float*)d_in[18],
    (const float*)d_in[19], (const float*)d_in[20], (const float*)d_in[21],
    (float*)d_out, (float*)d_ws);
}

// Round 3
// 13165.115 us; speedup vs baseline: 3.5933x; 3.5933x over previous
//
#include <hip/hip_runtime.h>
#include <cstdint>
#include <cstddef>

// ---------------------------------------------------------------------------
// Tacotron2-style decoder, persistent kernel. 256 blocks x 512 threads.
// Grid barrier: hierarchical relaxed atomics + single release/acquire fence.
// ---------------------------------------------------------------------------

#define NB 256
#define NT 512

#define Bz   8
#define TE   512
#define DINz 512
#define TDz  150
#define ODz  80
#define DRz  1024
#define PREz 256
#define ATz  128
#define LOCz 32
#define KFz  31

// workspace offsets (floats)
#define OF_P    0            // prenet [150*8][256]
#define OF_Q    307200       // q [128][8]
#define OF_U    308224       // u [8][512]
#define OF_CUM  312320       // att_cum [8][512]
#define OF_ATTC 316416       // unnormalized att_c [2][8][512]
#define OF_S    324608       // S [2][8]
#define OF_INVS 324624       // 1/S [2][8]
#define OF_H0   324640       // h0,c0,h1,c1 [8][1024] each; then gh0,gh1 [4096][8]
#define OF_C0   332832
#define OF_H1   341024
#define OF_C1   349216
#define OF_GH0  357408
#define OF_GH1  390176
#define OF_BAR  422944       // 640 ints

// shared memory (floats)
#define SM_WT 0       // W tile 32x256
#define SM_XT 8192    // X tile 8x256
#define SM_G  10240   // gate exchange 256
#define SM_TOT 10496  // 41984 B

__device__ __forceinline__ float fsig_(float x){ return 1.f/(1.f + __expf(-x)); }
__device__ __forceinline__ float ftanh_(float x){
  x = fminf(10.f, fmaxf(-10.f, x));
  float e = __expf(2.f*x);
  return (e - 1.f) / (e + 1.f);
}

// hierarchical grid barrier: monotonic counters (no reset, no ABA),
// ONE release fence before arrival, ONE acquire fence after wakeup,
// RELAXED spin (no per-poll buffer_inv!).
__device__ __forceinline__ void grid_barrier(int* bar){
  __syncthreads();
  if (threadIdx.x == 0){
    __builtin_amdgcn_fence(__ATOMIC_RELEASE, "agent");
    int* leaf  = bar + ((blockIdx.x >> 4) << 5);   // 16 leaves, 128B apart
    int* root  = bar + 512;
    int* epoch = bar + 544;
    int g = __hip_atomic_load(epoch, __ATOMIC_RELAXED, __HIP_MEMORY_SCOPE_AGENT);
    int lo = __hip_atomic_fetch_add(leaf, 1, __ATOMIC_RELAXED, __HIP_MEMORY_SCOPE_AGENT);
    if ((lo & 15) == 15){
      int ro = __hip_atomic_fetch_add(root, 1, __ATOMIC_RELAXED, __HIP_MEMORY_SCOPE_AGENT);
      if ((ro & 15) == 15)
        __hip_atomic_store(epoch, g + 1, __ATOMIC_RELAXED, __HIP_MEMORY_SCOPE_AGENT);
    }
    while (__hip_atomic_load(epoch, __ATOMIC_RELAXED, __HIP_MEMORY_SCOPE_AGENT) == g)
      __builtin_amdgcn_s_sleep(1);
    __builtin_amdgcn_fence(__ATOMIC_ACQUIRE, "agent");
  }
  __syncthreads();
}

// GEMM tile: out[row(0..31)][b(0..7)] = sum_k W[maprow(row)][kofs+k] * X[b][kofs+k]
// NT=512: thread = pos(0..15)*32 + s(0..31); pos owns rows {2pos,2pos+1}.
// K chunks of 256; register-prefetch software pipeline; b128 LDS compute.
// Returns value for (row32 = tid>>3, b = tid&7) on tid<256.
__device__ float gemm32x8(
    float* sm, const float* __restrict__ Wbase,
    int gatemap, int u0, int rowbase, int K, int nch, int kofs,
    int xmode, const float* __restrict__ xsrc,
    const float* __restrict__ attc_cur, const float* __restrict__ invS_cur,
    const float* __restrict__ Pt)
{
  const int tid = threadIdx.x;
  const int s = tid & 31, pos = tid >> 5;
  float acc[2][8];
  #pragma unroll
  for (int i=0;i<2;++i){
    #pragma unroll
    for (int b=0;b<8;++b) acc[i][b] = 0.f;
  }
  // staging addresses
  const float* wptr[4]; int wr4[4], wc4[4];
  #pragma unroll
  for (int it=0; it<4; ++it){
    int idx4 = tid + (it<<9);
    int r = idx4 >> 6, col = (idx4 & 63) << 2;
    int grow = gatemap ? (((r>>3)<<10) + u0 + (r&7)) : (rowbase + r);
    wptr[it] = Wbase + (size_t)grow*K + kofs + col;
    wr4[it] = r; wc4[it] = col;
  }
  const int xb = tid >> 6, xcol = (tid & 63) << 2;
  float xsc = 1.f;
  if (xmode == 1) xsc = __hip_atomic_load((const float*)invS_cur + xb,
                        __ATOMIC_RELAXED, __HIP_MEMORY_SCOPE_AGENT);
  float4 wreg[4], xreg;
  // prefetch chunk 0
  #pragma unroll
  for (int it=0;it<4;++it) wreg[it] = *(const float4*)(wptr[it]);
  {
    if (xmode == 0) xreg = *(const float4*)(xsrc + (size_t)xb*K + kofs + xcol);
    else { float4 v = *(const float4*)(attc_cur + (xb<<9) + xcol);
           v.x*=xsc; v.y*=xsc; v.z*=xsc; v.w*=xsc; xreg = v; }
  }
  for (int ch=0; ch<nch; ++ch){
    __syncthreads();
    #pragma unroll
    for (int it=0;it<4;++it)
      *(float4*)&sm[SM_WT + (wr4[it]<<8) + wc4[it]] = wreg[it];
    *(float4*)&sm[SM_XT + (xb<<8) + xcol] = xreg;
    __syncthreads();
    if (ch+1 < nch){
      const int c1 = (ch+1) << 8;
      #pragma unroll
      for (int it=0;it<4;++it) wreg[it] = *(const float4*)(wptr[it] + c1);
      if (xmode == 0) xreg = *(const float4*)(xsrc + (size_t)xb*K + kofs + c1 + xcol);
      else if (ch+1 < 2){ float4 v = *(const float4*)(attc_cur + (xb<<9) + c1 + xcol);
                          v.x*=xsc; v.y*=xsc; v.z*=xsc; v.w*=xsc; xreg = v; }
      else xreg = *(const float4*)(Pt + (xb<<8) + xcol);
    }
    #pragma unroll
    for (int j=0;j<2;++j){
      const int k = (j<<7) + (s<<2);
      float4 xv[8];
      #pragma unroll
      for (int b=0;b<8;++b) xv[b] = *(const float4*)&sm[SM_XT + (b<<8) + k];
      #pragma unroll
      for (int i=0;i<2;++i){
        float4 wv = *(const float4*)&sm[SM_WT + (((pos<<1)+i)<<8) + k];
        #pragma unroll
        for (int b=0;b<8;++b){
          acc[i][b] = fmaf(wv.x, xv[b].x, acc[i][b]);
          acc[i][b] = fmaf(wv.y, xv[b].y, acc[i][b]);
          acc[i][b] = fmaf(wv.z, xv[b].z, acc[i][b]);
          acc[i][b] = fmaf(wv.w, xv[b].w, acc[i][b]);
        }
      }
    }
  }
  __syncthreads();   // LDS free before reduction overwrite
  #pragma unroll
  for (int i=0;i<2;++i){
    #pragma unroll
    for (int b=0;b<8;++b){
      int ridx = ((((pos<<1)+i)<<3) | b);
      sm[ridx*33 + s] = acc[i][b];
    }
  }
  __syncthreads();
  float sum = 0.f;
  if (tid < 256){
    #pragma unroll
    for (int s2=0;s2<32;++s2) sum += sm[tid*33 + s2];
  }
  return sum;
}

__device__ void lstm_epilogue(float* sm, float dot,
                              const float* __restrict__ bias,
                              const float* __restrict__ gh,
                              float* __restrict__ h, float* __restrict__ c, int u0)
{
  const int tid = threadIdx.x;
  if (tid < 256){
    int row32 = tid >> 3, b = tid & 7;
    int gate = row32 >> 3, ul = row32 & 7;
    int grow = (gate<<10) + u0 + ul;
    sm[SM_G + tid] = dot + bias[grow] + gh[(grow<<3) + b];
  }
  __syncthreads();
  if (tid < 64){
    float gi = sm[SM_G + tid];
    float gf = sm[SM_G + 64 + tid];
    float gg = sm[SM_G + 128 + tid];
    float go = sm[SM_G + 192 + tid];
    int ul2 = tid >> 3, b2 = tid & 7;
    int hi = (b2<<10) + u0 + ul2;
    float co = c[hi], ho = h[hi];
    float cn = fsig_(gf)*co + fsig_(gi)*ftanh_(gg);
    float hn = fsig_(go)*ftanh_(cn);
    c[hi] = 0.9f*cn + 0.1f*co;
    h[hi] = 0.9f*hn + 0.1f*ho;
  }
}

// one output row per wave: rr = b*81 + r (r==80 -> stop)
__device__ void outstop_wave(int rr, int tp, int par,
    const float* __restrict__ feat_W, const float* __restrict__ stop_W,
    const float* __restrict__ stop_b, const float* __restrict__ h1,
    const float* __restrict__ attc, const float* __restrict__ iSw,
    float* __restrict__ d_out)
{
  if (rr >= 648) return;
  int b = rr / 81, r = rr - 81*b;
  int lane = threadIdx.x & 63;
  const float4* Wr = (const float4*)((r < 80) ? (feat_W + (size_t)r*1536) : stop_W);
  const float4* h4 = (const float4*)(h1 + (b<<10));
  const float4* a4 = (const float4*)(attc + (par<<12) + (b<<9));
  float inv = __hip_atomic_load((const float*)iSw + (par<<3) + b,
               __ATOMIC_RELAXED, __HIP_MEMORY_SCOPE_AGENT);
  float acc = 0.f, acc2 = 0.f;
  #pragma unroll
  for (int j=0;j<4;++j){
    int p = lane + (j<<6);
    float4 w = Wr[p], x = h4[p];
    acc = fmaf(w.x,x.x, fmaf(w.y,x.y, fmaf(w.z,x.z, fmaf(w.w,x.w, acc))));
  }
  #pragma unroll
  for (int j=4;j<6;++j){
    int p = lane + (j<<6);
    float4 w = Wr[p], x = a4[p-256];
    acc2 = fmaf(w.x,x.x, fmaf(w.y,x.y, fmaf(w.z,x.z, fmaf(w.w,x.w, acc2))));
  }
  acc += acc2 * inv;
  acc += __shfl_down(acc, 32, 64);
  acc += __shfl_down(acc, 16, 64);
  acc += __shfl_down(acc,  8, 64);
  acc += __shfl_down(acc,  4, 64);
  acc += __shfl_down(acc,  2, 64);
  acc += __shfl_down(acc,  1, 64);
  if (lane == 0){
    if (r < 80) d_out[((size_t)b*TDz + tp)*ODz + r] = acc;
    else        d_out[96000 + (size_t)b*TDz + tp] = acc + stop_b[0];
  }
}

extern "C" __global__ void __launch_bounds__(NT, 2) dec_kernel(
  const float* __restrict__ memory, const int* __restrict__ mlen, const float* __restrict__ targets,
  const float* __restrict__ W_mem, const float* __restrict__ W_q, const float* __restrict__ W_loc,
  const float* __restrict__ loc_f, const float* __restrict__ attn_v, const float* __restrict__ attn_b,
  const float* __restrict__ pre_W1, const float* __restrict__ pre_b1,
  const float* __restrict__ pre_W2, const float* __restrict__ pre_b2,
  const float* __restrict__ Wi0, const float* __restrict__ Wh0, const float* __restrict__ bl0,
  const float* __restrict__ Wi1, const float* __restrict__ Wh1, const float* __restrict__ bl1,
  const float* __restrict__ feat_W, const float* __restrict__ stop_W, const float* __restrict__ stop_b,
  float* __restrict__ d_out, float* __restrict__ ws)
{
  __shared__ float sm[SM_TOT];
  const int blk = blockIdx.x, tid = threadIdx.x;

  float* Pw   = ws + OF_P;
  float* qw   = ws + OF_Q;
  float* uw   = ws + OF_U;
  float* cum  = ws + OF_CUM;
  float* attc = ws + OF_ATTC;
  float* Sw   = ws + OF_S;
  float* iSw  = ws + OF_INVS;
  float* h0 = ws + OF_H0; float* c0 = ws + OF_C0;
  float* h1 = ws + OF_H1; float* c1 = ws + OF_C1;
  float* gh0 = ws + OF_GH0; float* gh1 = ws + OF_GH1;
  int* bar = (int*)(ws + OF_BAR);

  // persistent attention registers (a = tid&127 fixed for whole kernel)
  const int pa  = tid & 127;    // attention feature index
  const int ilg = tid >> 7;     // position group (0..3)
  float freg[KFz], pmreg[4], vreg;

  // ------------------------- INIT (every launch) ---------------------------
  {
    const int gs = NB*NT;
    int gid = blk*NT + tid;
    for (int i = gid; i < 98304; i += gs) h0[i] = 0.f;   // h0..gh1 contiguous
    for (int i = gid; i < 1024;  i += gs) qw[i] = 0.f;
    for (int i = gid; i < 4096;  i += gs) cum[i] = 0.f;
    if (gid < 32) Sw[gid] = 0.f;                          // S + invS

    // stage this block's 16 memory rows; compute pmreg (+bias) and freg, vreg
    int b = blk >> 5, i0 = (blk & 31) << 4;
    for (int idx = tid; idx < 8192; idx += NT)
      sm[idx] = memory[(size_t)((b<<9) + i0 + (idx>>9))*DINz + (idx & 511)];
    __syncthreads();
    {
      const float* wr = W_mem + (size_t)pa*DINz;
      #pragma unroll
      for (int j=0;j<4;++j){
        int il = (ilg<<2) + j;
        const float* mr = &sm[il<<9];
        float acc = 0.f;
        for (int d=0; d<DINz; d+=4){
          acc = fmaf(mr[d  ], wr[d  ], acc);
          acc = fmaf(mr[d+1], wr[d+1], acc);
          acc = fmaf(mr[d+2], wr[d+2], acc);
          acc = fmaf(mr[d+3], wr[d+3], acc);
        }
        pmreg[j] = acc + attn_b[pa];
      }
      for (int k=0;k<KFz;++k){
        float s2 = 0.f;
        #pragma unroll
        for (int c2=0;c2<LOCz;++c2) s2 = fmaf(W_loc[(pa<<5)+c2], loc_f[c2*KFz+k], s2);
        freg[k] = s2;
      }
      vreg = attn_v[pa];
    }
    __syncthreads();

    // prenet for all (t,b) pairs: pair = t*8+b; two half-blocks, 3 uniform iters
    const int th = tid >> 8, t2 = tid & 255, base = th << 10;
    for (int it=0; it<3; ++it){
      int pp = (blk<<1) + th + (it<<9);
      bool act = pp < 1200;
      if (act && t2 < ODz){
        int tt = pp >> 3, bb = pp & 7;
        sm[base + t2] = (tt==0) ? 0.f : targets[((size_t)bb*TDz + (tt-1))*ODz + t2];
      }
      __syncthreads();
      if (act){
        float a1 = pre_b1[t2];
        for (int k=0;k<ODz;++k) a1 = fmaf(pre_W1[t2*ODz+k], sm[base+k], a1);
        sm[base + 128 + t2] = fmaxf(a1, 0.f);
      }
      __syncthreads();
      if (act){
        float a2 = pre_b2[t2];
        for (int k=0;k<PREz;++k) a2 = fmaf(pre_W2[(t2<<8)+k], sm[base+128+k], a2);
        Pw[((size_t)pp<<8) + t2] = fmaxf(a2, 0.f);
      }
      __syncthreads();
    }
  }
  grid_barrier(bar);

  // ------------------------------ MAIN LOOP --------------------------------
  for (int t = 0; t < TDz; ++t){
    const int cur = t & 1, prv = cur ^ 1;

    // ---- P1: e -> u (unnormalized softmax) -------------------------------
    {
      int b = blk >> 5, i0 = (blk & 31) << 4;
      if (tid < 46){
        int gi = i0 - 15 + tid;
        sm[tid] = (gi >= 0 && gi < TE) ? cum[(b<<9)+gi] : 0.f;
      }
      if (tid >= 64 && tid < 192) sm[tid] = qw[((tid-64)<<3) + b];
      __syncthreads();
      float part[4];
      #pragma unroll
      for (int j=0;j<4;++j){
        int il = (ilg<<2) + j;
        float conv = 0.f;
        #pragma unroll
        for (int k=0;k<KFz;++k) conv = fmaf(freg[k], sm[il + k], conv);
        part[j] = vreg * ftanh_(pmreg[j] + sm[64 + pa] + conv);
      }
      #pragma unroll
      for (int j=0;j<4;++j){
        float v = part[j];
        v += __shfl_down(v, 32, 64);
        v += __shfl_down(v, 16, 64);
        v += __shfl_down(v,  8, 64);
        v += __shfl_down(v,  4, 64);
        v += __shfl_down(v,  2, 64);
        v += __shfl_down(v,  1, 64);
        if ((tid & 63) == 0){
          int w = tid >> 6;
          int il = ((w>>1)<<2) + j;
          sm[256 + (il<<1) + (w&1)] = v;
        }
      }
      __syncthreads();
      if (tid < 16){
        float e = sm[256 + (tid<<1)] + sm[257 + (tid<<1)];
        int gi = i0 + tid;
        float uu = (gi < mlen[b]) ? __expf(e) : 0.f;
        uw[(b<<9)+gi] = uu;
        sm[292 + tid] = uu;
      }
      __syncthreads();
      if (tid == 0){
        float ssum = 0.f;
        #pragma unroll
        for (int k=0;k<16;++k) ssum += sm[292+k];
        atomicAdd(&Sw[(cur<<3)+b], ssum);
      }
    }
    grid_barrier(bar);

    // ---- P2: att_w/cum (8) | att_c (64) | gh1 (128) | zero q,S ----------
    if (blk < 8){
      int b = blk;
      float Sv = __hip_atomic_load(&Sw[(cur<<3)+b], __ATOMIC_RELAXED, __HIP_MEMORY_SCOPE_AGENT);
      float inv = 1.f / Sv;
      if (tid == 0) iSw[(cur<<3)+b] = inv;
      for (int i = tid; i < TE; i += NT){
        float w = uw[(b<<9)+i] * inv;
        d_out[97200 + ((size_t)b*TDz + t)*TE + i] = w;
        cum[(b<<9)+i] += w;
      }
    } else if (blk < 72){
      int idx = blk - 8, b = idx >> 3, d0 = (idx & 7) << 6;
      for (int i = tid; i < TE; i += NT) sm[i] = uw[(b<<9)+i];
      __syncthreads();
      int dd = tid & 63, is = tid >> 6;
      float acc = 0.f;
      for (int i = is; i < TE; i += 8)
        acc = fmaf(sm[i], memory[(size_t)((b<<9)+i)*DINz + d0 + dd], acc);
      sm[512 + dd*9 + is] = acc;
      __syncthreads();
      if (tid < 64){
        float s2 = 0.f;
        #pragma unroll
        for (int k=0;k<8;++k) s2 += sm[512 + tid*9 + k];
        attc[(cur<<12) + (b<<9) + d0 + tid] = s2;
      }
    } else if (blk < 200){
      int tile = blk - 72;
      float dot = gemm32x8(sm, Wh1, 0, 0, tile<<5, DRz, 4, 0,
                           0, h1, nullptr, nullptr, nullptr);
      if (tid < 256) gh1[(tile<<8) + tid] = dot;
    } else if (blk == 200){
      for (int i = tid; i < 1024; i += NT) qw[i] = 0.f;
    } else if (blk == 201){
      if (tid < 8) Sw[(prv<<3)+tid] = 0.f;
    }
    grid_barrier(bar);

    // ---- P3: LSTM0 finalize (128) | out/stop for t-1 (81 blocks) ---------
    if (blk < 128){
      float dot = gemm32x8(sm, Wi0, 1, blk<<3, 0, 768, 3, 0,
                           1, nullptr, attc + (cur<<12), iSw + (cur<<3),
                           Pw + ((size_t)t<<11));
      lstm_epilogue(sm, dot, bl0, gh0, h0, c0, blk<<3);
    } else if (blk >= 129 && blk < 210){
      if (t > 0)
        outstop_wave((blk-129)*8 + (tid>>6), t-1, prv,
                     feat_W, stop_W, stop_b, h1, attc, iSw, d_out);
    }
    grid_barrier(bar);

    // ---- P4: LSTM1 finalize (128) | gh0_{t+1} (128) | q_{t+1} (16 units) -
    if (blk < 128){
      float dot = gemm32x8(sm, Wi1, 1, blk<<3, 0, DRz, 4, 0,
                           0, h0, nullptr, nullptr, nullptr);
      lstm_epilogue(sm, dot, bl1, gh1, h1, c1, blk<<3);
    } else {
      int tile = blk - 128;
      float dot = gemm32x8(sm, Wh0, 0, 0, tile<<5, DRz, 4, 0,
                           0, h0, nullptr, nullptr, nullptr);
      if (tid < 256) gh0[(tile<<8) + tid] = dot;
      if (blk >= 240){
        int u = blk - 240, rt = u >> 2, kc = u & 3;
        float d2 = gemm32x8(sm, W_q, 0, 0, rt<<5, DRz, 1, kc<<8,
                            0, h0, nullptr, nullptr, nullptr);
        if (tid < 256) atomicAdd(&qw[(rt<<8) + tid], d2);
      }
    }
    grid_barrier(bar);
  }

  // final out/stop for t = 149 (parity cur of t=149 is 1)
  if (blk >= 129 && blk < 210)
    outstop_wave((blk-129)*8 + (tid>>6), TDz-1, 1,
                 feat_W, stop_W, stop_b, h1, attc, iSw, d_out);
}

extern "C" void kernel_launch(void* const* d_in, const int* in_sizes, int n_in,
                              void* d_out, int out_size, void* d_ws, size_t ws_size,
                              hipStream_t stream)
{
  (void)in_sizes; (void)n_in; (void)out_size; (void)ws_size;
  (void)hipMemsetAsync((char*)d_ws + (size_t)OF_BAR*4, 0, 2560, stream);
  dec_kernel<<<dim3(NB), dim3(NT), 0, stream>>>(
    (const float*)d_in[0],  (const int*)d_in[1],   (const float*)d_in[2],
    (const float*)d_in[3],  (const float*)d_in[4],  (const float*)d_in[5],
    (const float*)d_in[6],  (const float*)d_in[7],  (const float*)d_in[8],
    (const float*)d_in[9],  (const float*)d_in[10], (const float*)d_in[11], (const float*)d_in[12],
    (const float*)d_in[13], (const float*)d_in[14], (const float*)d_in[15],
    (const float*)d_in[16], (const float*)d_in[17], (const float*)d_in[18],
    (const float*)d_in[19], (const float*)d_in[20], (const float*)d_in[21],
    (float*)d_out, (float*)d_ws);
}

// Round 4
// 11153.085 us; speedup vs baseline: 4.2416x; 1.1804x over previous
//
#include <hip/hip_runtime.h>
#include <cstdint>
#include <cstddef>

// ---------------------------------------------------------------------------
// Tacotron2-style decoder, persistent kernel. 256 blocks x 512 threads.
// Cross-block state goes through LLC via agent-scope relaxed atomics (sc1);
// barriers do NO cache maintenance, so weights stay L2-resident per block.
// ---------------------------------------------------------------------------

#define NB 256
#define NT 512

#define Bz   8
#define TE   512
#define DINz 512
#define TDz  150
#define ODz  80
#define DRz  1024
#define PREz 256
#define ATz  128
#define LOCz 32
#define KFz  31

// workspace offsets (floats)
#define OF_P    0            // prenet [1200][256]
#define OF_PM   307200       // pmT per attention block [64][128a][64il]
#define OF_Q    831488       // q [128][8]
#define OF_U    832512       // u [8][512]
#define OF_CUM  836608       // att_cum [8][512]
#define OF_ATTC 840704       // unnormalized att_c [2][8][512]
#define OF_S    848896       // S [2][8]
#define OF_INVS 848912       // 1/S [2][8]
#define OF_H0   848928
#define OF_C0   857120
#define OF_H1   865312
#define OF_C1   873504
#define OF_GH0  881696       // gh0 [4096][8]
#define OF_GH1  914464       // gh1 [4096][8]
#define OF_BAR  947232       // 640 ints

// shared memory (floats) -- gemm layout
#define SM_WT 0       // W tile 32x256
#define SM_XT 8192    // X tile 8x256
#define SM_G  10240   // gate exchange 256
#define SM_TOT 10496  // 41984 B
// persistent slabs for attention blocks (blk<64) -- never touched by their
// other roles (attc uses sm[0..1100), outstop/attw use no LDS)
#define SMA_F   1280  // F[a*31+k]  (3968)
#define SMA_V   5248  // v[128]
#define SMA_CW  5376  // cum window 94
#define SMA_Q   5472  // q[128]
#define SMA_PART 5600 // partials [64il][8ag]
#define SMA_U   6112  // u stage 64
#define SMA_PRE 6400  // prenet scratch 2x512

#define AG __HIP_MEMORY_SCOPE_AGENT

__device__ __forceinline__ float ldg_sc1(const float* p){
  return __hip_atomic_load(p, __ATOMIC_RELAXED, AG);
}
__device__ __forceinline__ void stg_sc1(float* p, float v){
  __hip_atomic_store(p, v, __ATOMIC_RELAXED, AG);
}
__device__ __forceinline__ float4 ldg4_sc1(const float* p){
  float4 r; r.x=ldg_sc1(p); r.y=ldg_sc1(p+1); r.z=ldg_sc1(p+2); r.w=ldg_sc1(p+3);
  return r;
}

__device__ __forceinline__ float fsig_(float x){ return 1.f/(1.f + __expf(-x)); }
__device__ __forceinline__ float ftanh_(float x){
  x = fminf(10.f, fmaxf(-10.f, x));
  float e = __expf(2.f*x);
  return (e - 1.f) / (e + 1.f);
}

// light barrier: no cache maintenance. All communication is sc1 (LLC).
__device__ __forceinline__ void grid_barrier(int* bar){
  asm volatile("s_waitcnt vmcnt(0) lgkmcnt(0)" ::: "memory");
  __syncthreads();
  if (threadIdx.x == 0){
    int* leaf  = bar + ((blockIdx.x >> 4) << 5);
    int* root  = bar + 512;
    int* epoch = bar + 544;
    int g = __hip_atomic_load(epoch, __ATOMIC_RELAXED, AG);
    int lo = __hip_atomic_fetch_add(leaf, 1, __ATOMIC_RELAXED, AG);
    if ((lo & 15) == 15){
      int ro = __hip_atomic_fetch_add(root, 1, __ATOMIC_RELAXED, AG);
      if ((ro & 15) == 15)
        __hip_atomic_store(epoch, g + 1, __ATOMIC_RELAXED, AG);
    }
    while (__hip_atomic_load(epoch, __ATOMIC_RELAXED, AG) == g)
      __builtin_amdgcn_s_sleep(1);
  }
  __syncthreads();
}

// heavy barrier (once, after init): flush init's cached writes to LLC/HBM.
__device__ __forceinline__ void grid_barrier_heavy(int* bar){
  asm volatile("s_waitcnt vmcnt(0) lgkmcnt(0)" ::: "memory");
  __syncthreads();
  if (threadIdx.x == 0){
    __builtin_amdgcn_fence(__ATOMIC_RELEASE, "agent");
    int* leaf  = bar + ((blockIdx.x >> 4) << 5);
    int* root  = bar + 512;
    int* epoch = bar + 544;
    int g = __hip_atomic_load(epoch, __ATOMIC_RELAXED, AG);
    int lo = __hip_atomic_fetch_add(leaf, 1, __ATOMIC_RELAXED, AG);
    if ((lo & 15) == 15){
      int ro = __hip_atomic_fetch_add(root, 1, __ATOMIC_RELAXED, AG);
      if ((ro & 15) == 15)
        __hip_atomic_store(epoch, g + 1, __ATOMIC_RELAXED, AG);
    }
    while (__hip_atomic_load(epoch, __ATOMIC_RELAXED, AG) == g)
      __builtin_amdgcn_s_sleep(1);
    __builtin_amdgcn_fence(__ATOMIC_ACQUIRE, "agent");
  }
  __syncthreads();
}

// GEMM: out[row 0..31][b 0..7] = sum_k W[maprow(row)][k] * X[b][k]
// W cached (L2-warm, same tile every step); X via sc1 (fresh from LLC).
__device__ float gemm32x8(
    float* sm, const float* __restrict__ Wbase,
    int gatemap, int u0, int rowbase, int K, int nch,
    int xmode, const float* __restrict__ xsrc,
    const float* __restrict__ attc_cur, const float* __restrict__ invS_cur,
    const float* __restrict__ Pt)
{
  const int tid = threadIdx.x;
  const int s = tid & 31, pos = tid >> 5;
  float acc[2][8];
  #pragma unroll
  for (int i=0;i<2;++i){
    #pragma unroll
    for (int b=0;b<8;++b) acc[i][b] = 0.f;
  }
  const float* wptr[4]; int wr4[4], wc4[4];
  #pragma unroll
  for (int it=0; it<4; ++it){
    int idx4 = tid + (it<<9);
    int r = idx4 >> 6, col = (idx4 & 63) << 2;
    int grow = gatemap ? (((r>>3)<<10) + u0 + (r&7)) : (rowbase + r);
    wptr[it] = Wbase + (size_t)grow*K + col;
    wr4[it] = r; wc4[it] = col;
  }
  const int xb = tid >> 6, xcol = (tid & 63) << 2;
  float xsc = (xmode == 1) ? ldg_sc1(invS_cur + xb) : 1.f;
  float4 wreg[4], xreg;
  #pragma unroll
  for (int it=0;it<4;++it) wreg[it] = *(const float4*)(wptr[it]);
  {
    if (xmode == 0) xreg = ldg4_sc1(xsrc + (size_t)xb*K + xcol);
    else { float4 v = ldg4_sc1(attc_cur + (xb<<9) + xcol);
           v.x*=xsc; v.y*=xsc; v.z*=xsc; v.w*=xsc; xreg = v; }
  }
  for (int ch=0; ch<nch; ++ch){
    __syncthreads();
    #pragma unroll
    for (int it=0;it<4;++it)
      *(float4*)&sm[SM_WT + (wr4[it]<<8) + wc4[it]] = wreg[it];
    *(float4*)&sm[SM_XT + (xb<<8) + xcol] = xreg;
    __syncthreads();
    if (ch+1 < nch){
      const int c1 = (ch+1) << 8;
      #pragma unroll
      for (int it=0;it<4;++it) wreg[it] = *(const float4*)(wptr[it] + c1);
      if (xmode == 0) xreg = ldg4_sc1(xsrc + (size_t)xb*K + c1 + xcol);
      else if (ch+1 < 2){ float4 v = ldg4_sc1(attc_cur + (xb<<9) + c1 + xcol);
                          v.x*=xsc; v.y*=xsc; v.z*=xsc; v.w*=xsc; xreg = v; }
      else xreg = *(const float4*)(Pt + (xb<<8) + xcol);
    }
    #pragma unroll
    for (int j=0;j<2;++j){
      const int k = (j<<7) + (s<<2);
      float4 xv[8];
      #pragma unroll
      for (int b=0;b<8;++b) xv[b] = *(const float4*)&sm[SM_XT + (b<<8) + k];
      #pragma unroll
      for (int i=0;i<2;++i){
        float4 wv = *(const float4*)&sm[SM_WT + (((pos<<1)+i)<<8) + k];
        #pragma unroll
        for (int b=0;b<8;++b){
          acc[i][b] = fmaf(wv.x, xv[b].x, acc[i][b]);
          acc[i][b] = fmaf(wv.y, xv[b].y, acc[i][b]);
          acc[i][b] = fmaf(wv.z, xv[b].z, acc[i][b]);
          acc[i][b] = fmaf(wv.w, xv[b].w, acc[i][b]);
        }
      }
    }
  }
  __syncthreads();
  #pragma unroll
  for (int i=0;i<2;++i){
    #pragma unroll
    for (int b=0;b<8;++b){
      int ridx = ((((pos<<1)+i)<<3) | b);
      sm[ridx*33 + s] = acc[i][b];
    }
  }
  __syncthreads();
  float sum = 0.f;
  if (tid < 256){
    #pragma unroll
    for (int s2=0;s2<32;++s2) sum += sm[tid*33 + s2];
  }
  return sum;
}

__device__ void lstm_epilogue(float* sm, float dot,
                              const float* __restrict__ bias,
                              const float* __restrict__ gh,
                              float* __restrict__ h, float* __restrict__ c, int u0)
{
  const int tid = threadIdx.x;
  if (tid < 256){
    int row32 = tid >> 3, b = tid & 7;
    int gate = row32 >> 3, ul = row32 & 7;
    int grow = (gate<<10) + u0 + ul;
    sm[SM_G + tid] = dot + bias[grow] + ldg_sc1(&gh[(grow<<3) + b]);
  }
  __syncthreads();
  if (tid < 64){
    float gi = sm[SM_G + tid];
    float gf = sm[SM_G + 64 + tid];
    float gg = sm[SM_G + 128 + tid];
    float go = sm[SM_G + 192 + tid];
    int ul2 = tid >> 3, b2 = tid & 7;
    int hi = (b2<<10) + u0 + ul2;
    float co = c[hi];               // block-private: cached
    float ho = ldg_sc1(&h[hi]);     // shared: sc1
    float cn = fsig_(gf)*co + fsig_(gi)*ftanh_(gg);
    float hn = fsig_(go)*ftanh_(cn);
    c[hi] = 0.9f*cn + 0.1f*co;
    stg_sc1(&h[hi], 0.9f*hn + 0.1f*ho);
  }
}

// one output row per wave: rr = b*81 + r (r==80 -> stop)
__device__ void outstop_wave(int rr, int tp, int par,
    const float* __restrict__ feat_W, const float* __restrict__ stop_W,
    const float* __restrict__ stop_b, const float* __restrict__ h1,
    const float* __restrict__ attc, const float* __restrict__ iSw,
    float* __restrict__ d_out)
{
  if (rr >= 648) return;
  int b = rr / 81, r = rr - 81*b;
  int lane = threadIdx.x & 63;
  const float4* Wr = (const float4*)((r < 80) ? (feat_W + (size_t)r*1536) : stop_W);
  float inv = ldg_sc1(iSw + (par<<3) + b);
  float acc = 0.f, acc2 = 0.f;
  #pragma unroll
  for (int j=0;j<4;++j){
    int p = lane + (j<<6);
    float4 w = Wr[p], x = ldg4_sc1(h1 + (b<<10) + (p<<2));
    acc = fmaf(w.x,x.x, fmaf(w.y,x.y, fmaf(w.z,x.z, fmaf(w.w,x.w, acc))));
  }
  #pragma unroll
  for (int j=4;j<6;++j){
    int p = lane + (j<<6);
    float4 w = Wr[p], x = ldg4_sc1(attc + (par<<12) + (b<<9) + ((p-256)<<2));
    acc2 = fmaf(w.x,x.x, fmaf(w.y,x.y, fmaf(w.z,x.z, fmaf(w.w,x.w, acc2))));
  }
  acc += acc2 * inv;
  acc += __shfl_down(acc, 32, 64);
  acc += __shfl_down(acc, 16, 64);
  acc += __shfl_down(acc,  8, 64);
  acc += __shfl_down(acc,  4, 64);
  acc += __shfl_down(acc,  2, 64);
  acc += __shfl_down(acc,  1, 64);
  if (lane == 0){
    if (r < 80) d_out[((size_t)b*TDz + tp)*ODz + r] = acc;
    else        d_out[96000 + (size_t)b*TDz + tp] = acc + stop_b[0];
  }
}

extern "C" __global__ void __launch_bounds__(NT, 2) dec_kernel(
  const float* __restrict__ memory, const int* __restrict__ mlen, const float* __restrict__ targets,
  const float* __restrict__ W_mem, const float* __restrict__ W_q, const float* __restrict__ W_loc,
  const float* __restrict__ loc_f, const float* __restrict__ attn_v, const float* __restrict__ attn_b,
  const float* __restrict__ pre_W1, const float* __restrict__ pre_b1,
  const float* __restrict__ pre_W2, const float* __restrict__ pre_b2,
  const float* __restrict__ Wi0, const float* __restrict__ Wh0, const float* __restrict__ bl0,
  const float* __restrict__ Wi1, const float* __restrict__ Wh1, const float* __restrict__ bl1,
  const float* __restrict__ feat_W, const float* __restrict__ stop_W, const float* __restrict__ stop_b,
  float* __restrict__ d_out, float* __restrict__ ws)
{
  __shared__ float sm[SM_TOT];
  const int blk = blockIdx.x, tid = threadIdx.x;

  float* Pw   = ws + OF_P;
  float* pmT  = ws + OF_PM;
  float* qw   = ws + OF_Q;
  float* uw   = ws + OF_U;
  float* cum  = ws + OF_CUM;
  float* attc = ws + OF_ATTC;
  float* Sw   = ws + OF_S;
  float* iSw  = ws + OF_INVS;
  float* h0 = ws + OF_H0; float* c0 = ws + OF_C0;
  float* h1 = ws + OF_H1; float* c1 = ws + OF_C1;
  float* gh0 = ws + OF_GH0; float* gh1 = ws + OF_GH1;
  int* bar = (int*)(ws + OF_BAR);

  const bool is_attn = (blk < 64);
  const int ab  = blk >> 3;          // attention batch
  const int ai0 = (blk & 7) << 6;    // attention base position
  const int il  = tid & 63;          // attention position within block
  const int ag  = tid >> 6;          // attention feature group (0..7)

  // ------------------------- INIT (every launch) ---------------------------
  {
    const int gs = NB*NT;
    int gid = blk*NT + tid;
    for (int i = gid; i < 32768; i += gs) h0[i] = 0.f;   // h0,c0,h1,c1
    for (int i = gid; i < 1024;  i += gs) qw[i]  = 0.f;
    for (int i = gid; i < 4096;  i += gs) cum[i] = 0.f;
    if (gid < 32) Sw[gid] = 0.f;                          // S + invS

    if (is_attn){
      // pmT[a][il] = mem[ab, ai0+il, :] . W_mem[a,:] + attn_b[a]
      float pacc[16];
      #pragma unroll
      for (int j=0;j<16;++j) pacc[j] = 0.f;
      for (int dc=0; dc<4; ++dc){
        for (int idx = tid; idx < 8192; idx += NT){
          int r = idx >> 7, d = idx & 127;
          sm[r*129 + d] = memory[(size_t)((ab<<9)+ai0+r)*DINz + (dc<<7) + d];
        }
        __syncthreads();
        #pragma unroll
        for (int j=0;j<16;++j){
          int a = (ag<<4) + j;
          const float* wr = W_mem + (size_t)a*DINz + (dc<<7);  // wave-uniform
          const float* mr = &sm[il*129];
          float acc = 0.f;
          for (int d=0; d<128; d+=4){
            acc = fmaf(mr[d  ], wr[d  ], acc);
            acc = fmaf(mr[d+1], wr[d+1], acc);
            acc = fmaf(mr[d+2], wr[d+2], acc);
            acc = fmaf(mr[d+3], wr[d+3], acc);
          }
          pacc[j] += acc;
        }
        __syncthreads();
      }
      #pragma unroll
      for (int j=0;j<16;++j){
        int a = (ag<<4) + j;
        pmT[((size_t)blk<<13) + (a<<6) + il] = pacc[j] + attn_b[a];
      }
      // persistent LDS slabs: F = W_loc @ filters, v
      for (int idx = tid; idx < ATz*KFz; idx += NT){
        int a = idx / KFz, k = idx - a*KFz;
        float s2 = 0.f;
        #pragma unroll
        for (int c2=0;c2<LOCz;++c2) s2 = fmaf(W_loc[(a<<5)+c2], loc_f[c2*KFz+k], s2);
        sm[SMA_F + idx] = s2;
      }
      if (tid < 128) sm[SMA_V + tid] = attn_v[tid];
      __syncthreads();
    }

    // prenet for all (t,b) pairs, scratch at SMA_PRE (above persistent slabs)
    const int th = tid >> 8, t2 = tid & 255, base = SMA_PRE + (th<<9);
    for (int it=0; it<3; ++it){
      int pp = (blk<<1) + th + (it<<9);
      bool act = pp < 1200;
      if (act && t2 < ODz){
        int tt = pp >> 3, bb = pp & 7;
        sm[base + t2] = (tt==0) ? 0.f : targets[((size_t)bb*TDz + (tt-1))*ODz + t2];
      }
      __syncthreads();
      if (act){
        float a1 = pre_b1[t2];
        for (int k=0;k<ODz;++k) a1 = fmaf(pre_W1[t2*ODz+k], sm[base+k], a1);
        sm[base + 128 + t2] = fmaxf(a1, 0.f);
      }
      __syncthreads();
      if (act){
        float a2 = pre_b2[t2];
        for (int k=0;k<PREz;++k) a2 = fmaf(pre_W2[(t2<<8)+k], sm[base+128+k], a2);
        Pw[((size_t)pp<<8) + t2] = fmaxf(a2, 0.f);
      }
      __syncthreads();
    }
  }
  grid_barrier_heavy(bar);

  // ------------------------------ MAIN LOOP --------------------------------
  for (int t = 0; t < TDz; ++t){
    const int cur = t & 1, prv = cur ^ 1;

    // ---- P1: attention u (blk 0-63) | gh0 = Wh0 @ h0(t-1) (blk 64-191) ----
    if (is_attn){
      if (tid < 94){
        int gi = ai0 - 15 + tid;
        sm[SMA_CW + tid] = (gi >= 0 && gi < TE) ? ldg_sc1(&cum[(ab<<9)+gi]) : 0.f;
      }
      if (tid < 128) sm[SMA_Q + tid] = ldg_sc1(&qw[(tid<<3) + ab]);
      __syncthreads();
      float part = 0.f;
      #pragma unroll
      for (int j=0;j<16;++j){
        int a = (ag<<4) + j;
        const float* fb = &sm[SMA_F + a*KFz];
        float conv = 0.f;
        #pragma unroll
        for (int k=0;k<KFz;++k) conv = fmaf(fb[k], sm[SMA_CW + il + k], conv);
        float pv = pmT[((size_t)blk<<13) + (a<<6) + il];
        part = fmaf(sm[SMA_V + a], ftanh_(pv + sm[SMA_Q + a] + conv), part);
      }
      sm[SMA_PART + (il<<3) + ag] = part;
      __syncthreads();
      if (tid < 64){
        float e = 0.f;
        #pragma unroll
        for (int k=0;k<8;++k) e += sm[SMA_PART + (tid<<3) + k];
        int gi = ai0 + tid;
        float uu = (gi < mlen[ab]) ? __expf(e) : 0.f;
        stg_sc1(&uw[(ab<<9)+gi], uu);
        sm[SMA_U + tid] = uu;
      }
      __syncthreads();
      if (tid == 0){
        float ssum = 0.f;
        #pragma unroll
        for (int k=0;k<64;++k) ssum += sm[SMA_U + k];
        atomicAdd(&Sw[(cur<<3)+ab], ssum);
      }
    } else if (blk < 192){
      int tile = blk - 64;
      float dot = gemm32x8(sm, Wh0, 0, 0, tile<<5, DRz, 4,
                           0, h0, nullptr, nullptr, nullptr);
      if (tid < 256) stg_sc1(&gh0[(tile<<8) + tid], dot);
    }
    grid_barrier(bar);

    // ---- P2: attw/cum (0-7) | attc (8-71) | gh1 (72-199) | S-zero (200) --
    if (blk < 8){
      int b = blk;
      float Sv = __hip_atomic_load(&Sw[(cur<<3)+b], __ATOMIC_RELAXED, AG);
      float inv = 1.f / Sv;
      if (tid == 0) stg_sc1(&iSw[(cur<<3)+b], inv);
      for (int i = tid; i < TE; i += NT){
        float u = ldg_sc1(&uw[(b<<9)+i]);
        float w = u * inv;
        d_out[97200 + ((size_t)b*TDz + t)*TE + i] = w;
        stg_sc1(&cum[(b<<9)+i], ldg_sc1(&cum[(b<<9)+i]) + w);
      }
    } else if (blk < 72){
      int idx = blk - 8, b = idx >> 3, d0 = (idx & 7) << 6;
      for (int i = tid; i < TE; i += NT) sm[i] = ldg_sc1(&uw[(b<<9)+i]);
      __syncthreads();
      int dd = tid & 63, is = tid >> 6;
      float acc = 0.f;
      for (int i = is; i < TE; i += 8)
        acc = fmaf(sm[i], memory[(size_t)((b<<9)+i)*DINz + d0 + dd], acc);
      sm[512 + dd*9 + is] = acc;
      __syncthreads();
      if (tid < 64){
        float s2 = 0.f;
        #pragma unroll
        for (int k=0;k<8;++k) s2 += sm[512 + tid*9 + k];
        stg_sc1(&attc[(cur<<12) + (b<<9) + d0 + tid], s2);
      }
    } else if (blk < 200){
      int tile = blk - 72;
      float dot = gemm32x8(sm, Wh1, 0, 0, tile<<5, DRz, 4,
                           0, h1, nullptr, nullptr, nullptr);
      if (tid < 256) stg_sc1(&gh1[(tile<<8) + tid], dot);
    } else if (blk == 200){
      if (tid < 8) stg_sc1(&Sw[(prv<<3)+tid], 0.f);
    }
    grid_barrier(bar);

    // ---- P3: outstop t-1 (blk 0-80) | LSTM0 (blk 128-255) ----------------
    if (blk < 81){
      if (t > 0)
        outstop_wave(blk*8 + (tid>>6), t-1, prv,
                     feat_W, stop_W, stop_b, h1, attc, iSw, d_out);
    } else if (blk >= 128){
      int u0 = (blk - 128) << 3;
      float dot = gemm32x8(sm, Wi0, 1, u0, 0, 768, 3,
                           1, nullptr, attc + (cur<<12), iSw + (cur<<3),
                           Pw + ((size_t)t<<11));
      lstm_epilogue(sm, dot, bl0, gh0, h0, c0, u0);
    }
    grid_barrier(bar);

    // ---- P4: Wq -> q(t+1) (blk 64-67) | LSTM1 (blk 128-255) --------------
    if (blk >= 64 && blk < 68){
      int rt = blk & 3;
      float dot = gemm32x8(sm, W_q, 0, 0, rt<<5, DRz, 4,
                           0, h0, nullptr, nullptr, nullptr);
      if (tid < 256) stg_sc1(&qw[(rt<<8) + tid], dot);
    } else if (blk >= 128){
      int u0 = (blk - 128) << 3;
      float dot = gemm32x8(sm, Wi1, 1, u0, 0, DRz, 4,
                           0, h0, nullptr, nullptr, nullptr);
      lstm_epilogue(sm, dot, bl1, gh1, h1, c1, u0);
    }
    grid_barrier(bar);
  }

  // final out/stop for t = 149 (parity of t=149 is 1)
  if (blk < 81)
    outstop_wave(blk*8 + (tid>>6), TDz-1, 1,
                 feat_W, stop_W, stop_b, h1, attc, iSw, d_out);
}

extern "C" void kernel_launch(void* const* d_in, const int* in_sizes, int n_in,
                              void* d_out, int out_size, void* d_ws, size_t ws_size,
                              hipStream_t stream)
{
  (void)in_sizes; (void)n_in; (void)out_size; (void)ws_size;
  (void)hipMemsetAsync((char*)d_ws + (size_t)OF_BAR*4, 0, 2560, stream);
  dec_kernel<<<dim3(NB), dim3(NT), 0, stream>>>(
    (const float*)d_in[0],  (const int*)d_in[1],   (const float*)d_in[2],
    (const float*)d_in[3],  (const float*)d_in[4],  (const float*)d_in[5],
    (const float*)d_in[6],  (const float*)d_in[7],  (const float*)d_in[8],
    (const float*)d_in[9],  (const float*)d_in[10], (const float*)d_in[11], (const float*)d_in[12],
    (const float*)d_in[13], (const float*)d_in[14], (const float*)d_in[15],
    (const float*)d_in[16], (const float*)d_in[17], (const float*)d_in[18],
    (const float*)d_in[19], (const float*)d_in[20], (const float*)d_in[21],
    (float*)d_out, (float*)d_ws);
}

// Round 9
// 9127.794 us; speedup vs baseline: 5.1827x; 1.2219x over previous
//
#include <hip/hip_runtime.h>
#include <hip/hip_fp16.h>
#include <cstdint>
#include <cstddef>

// ---------------------------------------------------------------------------
// Tacotron2-style decoder, persistent kernel. 256 blocks x 512 threads.
// 3 grid-barrier phases per step. LSTM weights converted to fp16 in ws,
// per-matrix, as capacity allows (host-computed fit mask; fp32 otherwise).
// Cross-block state via sc1 (LLC). S read directly by LSTM0 (no invS race).
// ---------------------------------------------------------------------------

#define NB 256
#define NT 512

#define Bz   8
#define TE   512
#define DINz 512
#define TDz  150
#define ODz  80
#define DRz  1024
#define PREz 256
#define ATz  128
#define LOCz 32
#define KFz  31

// workspace offsets (floats)
#define OF_P    0            // prenet [1200][256]
#define OF_PM   307200       // pmT per attention block [64][128a][64il]
#define OF_Q    831488       // q [128a][8b]
#define OF_U    832512       // u [8][512]
#define OF_CUM  836608       // att_cum [8][512]
#define OF_ATTC 840704       // unnormalized att_c [2][8][512] (atomic-accum)
#define OF_S    848896       // S [2][8]
#define OF_INVS 848912       // 1/S [2][8]
#define OF_H0   848928
#define OF_C0   857120
#define OF_H1   865312
#define OF_C1   873504
#define OF_GH0  881696       // gh0 [4096][8]
#define OF_GH1  914464       // gh1 [4096][8]
#define OF_BAR  947232       // 640 ints
#define OF_F16  947872       // fp16 weight region (halves): Wh0|Wh1|Wi1|Wi0
#define N_I0    3145728      // 4096*768
#define N_HH    4194304      // 4096*1024

// shared memory (floats)
#define SM_WT 0       // W tile: fp32 32x256 (8192f) OR fp16 32x256 (first 4096f)
#define SM_XT 8192    // X tile 8x256
#define SM_G  10240   // gate exchange 256
// persistent attention slabs (blk<64), above all GEMM areas
#define SMA_F    10496  // F[a*31+k] (3968)
#define SMA_V    14464  // v[128]
#define SMA_CW   14592  // cum window 96
#define SMA_Q    14688  // q[128]
#define SMA_PART 14816  // partials [64][8]
#define SMA_U    15328  // u stage 64
#define SM_TOT   15392  // 61568 B

#define AG __HIP_MEMORY_SCOPE_AGENT

__device__ __forceinline__ float ldg_sc1(const float* p){
  return __hip_atomic_load(p, __ATOMIC_RELAXED, AG);
}
__device__ __forceinline__ void stg_sc1(float* p, float v){
  __hip_atomic_store(p, v, __ATOMIC_RELAXED, AG);
}
__device__ __forceinline__ float4 ldg4_sc1(const float* p){
  float4 r; r.x=ldg_sc1(p); r.y=ldg_sc1(p+1); r.z=ldg_sc1(p+2); r.w=ldg_sc1(p+3);
  return r;
}
__device__ __forceinline__ float fsig_(float x){ return 1.f/(1.f + __expf(-x)); }
__device__ __forceinline__ float ftanh_(float x){
  x = fminf(10.f, fmaxf(-10.f, x));
  float e = __expf(2.f*x);
  return (e - 1.f) / (e + 1.f);
}

// light barrier: no cache maintenance (all comms are sc1/LLC)
__device__ __forceinline__ void grid_barrier(int* bar){
  asm volatile("s_waitcnt vmcnt(0) lgkmcnt(0)" ::: "memory");
  __syncthreads();
  if (threadIdx.x == 0){
    int* leaf  = bar + ((blockIdx.x >> 4) << 5);
    int* root  = bar + 512;
    int* epoch = bar + 544;
    int g = __hip_atomic_load(epoch, __ATOMIC_RELAXED, AG);
    int lo = __hip_atomic_fetch_add(leaf, 1, __ATOMIC_RELAXED, AG);
    if ((lo & 15) == 15){
      int ro = __hip_atomic_fetch_add(root, 1, __ATOMIC_RELAXED, AG);
      if ((ro & 15) == 15)
        __hip_atomic_store(epoch, g + 1, __ATOMIC_RELAXED, AG);
    }
    while (__hip_atomic_load(epoch, __ATOMIC_RELAXED, AG) == g)
      __builtin_amdgcn_s_sleep(1);
  }
  __syncthreads();
}
// heavy barrier (after init only): flush cached init writes, invalidate
__device__ __forceinline__ void grid_barrier_heavy(int* bar){
  asm volatile("s_waitcnt vmcnt(0) lgkmcnt(0)" ::: "memory");
  __syncthreads();
  if (threadIdx.x == 0){
    __builtin_amdgcn_fence(__ATOMIC_RELEASE, "agent");
    int* leaf  = bar + ((blockIdx.x >> 4) << 5);
    int* root  = bar + 512;
    int* epoch = bar + 544;
    int g = __hip_atomic_load(epoch, __ATOMIC_RELAXED, AG);
    int lo = __hip_atomic_fetch_add(leaf, 1, __ATOMIC_RELAXED, AG);
    if ((lo & 15) == 15){
      int ro = __hip_atomic_fetch_add(root, 1, __ATOMIC_RELAXED, AG);
      if ((ro & 15) == 15)
        __hip_atomic_store(epoch, g + 1, __ATOMIC_RELAXED, AG);
    }
    while (__hip_atomic_load(epoch, __ATOMIC_RELAXED, AG) == g)
      __builtin_amdgcn_s_sleep(1);
    __builtin_amdgcn_fence(__ATOMIC_ACQUIRE, "agent");
  }
  __syncthreads();
}

// GEMM tile: out[row 0..31][b 0..7] = sum_k W[maprow(row)][k] * X[b][k]
// F16: W staged as fp16 in LDS (b64 reads, v_cvt in-loop).
// xmode==1: X = [attc*(1/S) | prenet]; S_cur read directly (complete after P1).
template<bool F16>
__device__ float gemm32x8(
    float* sm, const void* Wv,
    int gatemap, int u0, int rowbase, int K, int nch,
    int xmode, const float* __restrict__ xsrc,
    const float* __restrict__ attc_cur, const float* __restrict__ S_cur,
    const float* __restrict__ Pt)
{
  const int tid = threadIdx.x;
  const int s = tid & 31, pos = tid >> 5;
  __half* smW16 = (__half*)sm;
  float acc[2][8];
  #pragma unroll
  for (int i=0;i<2;++i){
    #pragma unroll
    for (int b=0;b<8;++b) acc[i][b] = 0.f;
  }
  const __half* p16[2]; int st16[2];
  const float* p32[4]; int st32[4];
  if (F16){
    const __half* W16 = (const __half*)Wv;
    #pragma unroll
    for (int it=0; it<2; ++it){
      int idx = tid + (it<<9);
      int r = idx >> 5, g = idx & 31;
      int grow = gatemap ? (((r>>3)<<10) + u0 + (r&7)) : (rowbase + r);
      p16[it] = W16 + (size_t)grow*K + (g<<3);
      st16[it] = (r<<8) + (g<<3);
    }
  } else {
    const float* W32 = (const float*)Wv;
    #pragma unroll
    for (int it=0; it<4; ++it){
      int idx4 = tid + (it<<9);
      int r = idx4 >> 6, col = (idx4 & 63) << 2;
      int grow = gatemap ? (((r>>3)<<10) + u0 + (r&7)) : (rowbase + r);
      p32[it] = W32 + (size_t)grow*K + col;
      st32[it] = SM_WT + (r<<8) + col;
    }
  }
  const int xb = tid >> 6, xcol = (tid & 63) << 2;
  float xsc = 1.f;
  if (xmode == 1) xsc = 1.f / ldg_sc1(S_cur + xb);   // RACE FIX: read S, not invS
  uint4 w16r[2]; float4 w32r[4]; float4 xreg;
  // prefetch chunk 0
  if (F16){ w16r[0] = *(const uint4*)(p16[0]); w16r[1] = *(const uint4*)(p16[1]); }
  else {
    #pragma unroll
    for (int it=0;it<4;++it) w32r[it] = *(const float4*)(p32[it]);
  }
  if (xmode == 0) xreg = ldg4_sc1(xsrc + (size_t)xb*K + xcol);
  else { float4 v = ldg4_sc1(attc_cur + (xb<<9) + xcol);
         v.x*=xsc; v.y*=xsc; v.z*=xsc; v.w*=xsc; xreg = v; }
  for (int ch=0; ch<nch; ++ch){
    __syncthreads();
    if (F16){
      *(uint4*)&smW16[st16[0]] = w16r[0];
      *(uint4*)&smW16[st16[1]] = w16r[1];
    } else {
      #pragma unroll
      for (int it=0;it<4;++it) *(float4*)&sm[st32[it]] = w32r[it];
    }
    *(float4*)&sm[SM_XT + (xb<<8) + xcol] = xreg;
    __syncthreads();
    if (ch+1 < nch){
      const int c1 = (ch+1) << 8;
      if (F16){ w16r[0] = *(const uint4*)(p16[0] + c1); w16r[1] = *(const uint4*)(p16[1] + c1); }
      else {
        #pragma unroll
        for (int it=0;it<4;++it) w32r[it] = *(const float4*)(p32[it] + c1);
      }
      if (xmode == 0) xreg = ldg4_sc1(xsrc + (size_t)xb*K + c1 + xcol);
      else if (ch+1 < 2){ float4 v = ldg4_sc1(attc_cur + (xb<<9) + c1 + xcol);
                          v.x*=xsc; v.y*=xsc; v.z*=xsc; v.w*=xsc; xreg = v; }
      else xreg = *(const float4*)(Pt + (xb<<8) + xcol);
    }
    #pragma unroll
    for (int j=0;j<2;++j){
      const int k = (j<<7) + (s<<2);
      float4 xv[8];
      #pragma unroll
      for (int b=0;b<8;++b) xv[b] = *(const float4*)&sm[SM_XT + (b<<8) + k];
      #pragma unroll
      for (int i=0;i<2;++i){
        float4 wv;
        if (F16){
          uint2 w2 = *(const uint2*)&smW16[(((pos<<1)+i)<<8) + k];
          __half2 ha = *reinterpret_cast<const __half2*>(&w2.x);
          __half2 hb = *reinterpret_cast<const __half2*>(&w2.y);
          float2 fa = __half22float2(ha);
          float2 fb = __half22float2(hb);
          wv.x = fa.x; wv.y = fa.y; wv.z = fb.x; wv.w = fb.y;
        } else {
          wv = *(const float4*)&sm[SM_WT + (((pos<<1)+i)<<8) + k];
        }
        #pragma unroll
        for (int b=0;b<8;++b){
          acc[i][b] = fmaf(wv.x, xv[b].x, acc[i][b]);
          acc[i][b] = fmaf(wv.y, xv[b].y, acc[i][b]);
          acc[i][b] = fmaf(wv.z, xv[b].z, acc[i][b]);
          acc[i][b] = fmaf(wv.w, xv[b].w, acc[i][b]);
        }
      }
    }
  }
  __syncthreads();
  #pragma unroll
  for (int i=0;i<2;++i){
    #pragma unroll
    for (int b=0;b<8;++b){
      int ridx = ((((pos<<1)+i)<<3) | b);
      sm[ridx*33 + s] = acc[i][b];
    }
  }
  __syncthreads();
  float sum = 0.f;
  if (tid < 256){
    #pragma unroll
    for (int s2=0;s2<32;++s2) sum += sm[tid*33 + s2];
  }
  return sum;
}

__device__ void lstm_epilogue(float* sm, float dot,
                              const float* __restrict__ bias,
                              const float* __restrict__ gh,
                              float* __restrict__ h, float* __restrict__ c, int u0)
{
  const int tid = threadIdx.x;
  if (tid < 256){
    int row32 = tid >> 3, b = tid & 7;
    int gate = row32 >> 3, ul = row32 & 7;
    int grow = (gate<<10) + u0 + ul;
    sm[SM_G + tid] = dot + bias[grow] + ldg_sc1(&gh[(grow<<3) + b]);
  }
  __syncthreads();
  if (tid < 64){
    float gi = sm[SM_G + tid];
    float gf = sm[SM_G + 64 + tid];
    float gg = sm[SM_G + 128 + tid];
    float go = sm[SM_G + 192 + tid];
    int ul2 = tid >> 3, b2 = tid & 7;
    int hi = (b2<<10) + u0 + ul2;
    float co = c[hi];               // block-private: cached
    float ho = ldg_sc1(&h[hi]);     // shared: sc1
    float cn = fsig_(gf)*co + fsig_(gi)*ftanh_(gg);
    float hn = fsig_(go)*ftanh_(cn);
    c[hi] = 0.9f*cn + 0.1f*co;
    stg_sc1(&h[hi], 0.9f*hn + 0.1f*ho);
  }
}

// one output row per wave: rr = b*81 + r (r==80 -> stop)
__device__ void outstop_wave(int rr, int tp, int par,
    const float* __restrict__ feat_W, const float* __restrict__ stop_W,
    const float* __restrict__ stop_b, const float* __restrict__ h1,
    const float* __restrict__ attc, const float* __restrict__ iSw,
    float* __restrict__ d_out)
{
  if (rr >= 648) return;
  int b = rr / 81, r = rr - 81*b;
  int lane = threadIdx.x & 63;
  const float4* Wr = (const float4*)((r < 80) ? (feat_W + (size_t)r*1536) : stop_W);
  float inv = ldg_sc1(iSw + (par<<3) + b);
  float acc = 0.f, acc2 = 0.f;
  #pragma unroll
  for (int j=0;j<4;++j){
    int p = lane + (j<<6);
    float4 w = Wr[p], x = ldg4_sc1(h1 + (b<<10) + (p<<2));
    acc = fmaf(w.x,x.x, fmaf(w.y,x.y, fmaf(w.z,x.z, fmaf(w.w,x.w, acc))));
  }
  #pragma unroll
  for (int j=4;j<6;++j){
    int p = lane + (j<<6);
    float4 w = Wr[p], x = ldg4_sc1(attc + (par<<12) + (b<<9) + ((p-256)<<2));
    acc2 = fmaf(w.x,x.x, fmaf(w.y,x.y, fmaf(w.z,x.z, fmaf(w.w,x.w, acc2))));
  }
  acc += acc2 * inv;
  acc += __shfl_down(acc, 32, 64);
  acc += __shfl_down(acc, 16, 64);
  acc += __shfl_down(acc,  8, 64);
  acc += __shfl_down(acc,  4, 64);
  acc += __shfl_down(acc,  2, 64);
  acc += __shfl_down(acc,  1, 64);
  if (lane == 0){
    if (r < 80) d_out[((size_t)b*TDz + tp)*ODz + r] = acc;
    else        d_out[96000 + (size_t)b*TDz + tp] = acc + stop_b[0];
  }
}

extern "C" __global__ void __launch_bounds__(NT, 2) dec_kernel(
  const float* __restrict__ memory, const int* __restrict__ mlen, const float* __restrict__ targets,
  const float* __restrict__ W_mem, const float* __restrict__ W_q, const float* __restrict__ W_loc,
  const float* __restrict__ loc_f, const float* __restrict__ attn_v, const float* __restrict__ attn_b,
  const float* __restrict__ pre_W1, const float* __restrict__ pre_b1,
  const float* __restrict__ pre_W2, const float* __restrict__ pre_b2,
  const float* __restrict__ Wi0, const float* __restrict__ Wh0, const float* __restrict__ bl0,
  const float* __restrict__ Wi1, const float* __restrict__ Wh1, const float* __restrict__ bl1,
  const float* __restrict__ feat_W, const float* __restrict__ stop_W, const float* __restrict__ stop_b,
  float* __restrict__ d_out, float* __restrict__ ws, int wflags)
{
  __shared__ float sm[SM_TOT];
  const int blk = blockIdx.x, tid = threadIdx.x;

  float* Pw   = ws + OF_P;
  float* pmT  = ws + OF_PM;
  float* qw   = ws + OF_Q;
  float* uw   = ws + OF_U;
  float* cum  = ws + OF_CUM;
  float* attc = ws + OF_ATTC;
  float* Sw   = ws + OF_S;
  float* iSw  = ws + OF_INVS;
  float* h0 = ws + OF_H0; float* c0 = ws + OF_C0;
  float* h1 = ws + OF_H1; float* c1 = ws + OF_C1;
  float* gh0 = ws + OF_GH0; float* gh1 = ws + OF_GH1;
  int* bar = (int*)(ws + OF_BAR);
  __half* hbase = (__half*)(ws + OF_F16);        // Wh0|Wh1|Wi1|Wi0 (priority order)
  const __half* hWh0 = hbase;
  const __half* hWh1 = hbase + (size_t)N_HH;
  const __half* hWi1 = hbase + 2*(size_t)N_HH;
  const __half* hWi0 = hbase + 3*(size_t)N_HH;

  const bool is_attn = (blk < 64);
  const int ab  = blk >> 3;          // attention batch
  const int ai0 = (blk & 7) << 6;    // attention base position
  const int il  = tid & 63;          // position within slice
  const int ag  = tid >> 6;          // feature group (0..7)

  // ------------------------- INIT (every launch) ---------------------------
  {
    const int gs = NB*NT;
    int gid = blk*NT + tid;
    for (int i = gid; i < 32768; i += gs) h0[i] = 0.f;    // h0,c0,h1,c1
    for (int i = gid; i < 1024;  i += gs) qw[i]  = 0.f;
    for (int i = gid; i < 4096;  i += gs) cum[i] = 0.f;
    for (int i = gid; i < 8192;  i += gs) attc[i] = 0.f;
    if (gid < 32) Sw[gid] = 0.f;                          // S + invS

    if (wflags & 1) for (int i = gid; i < N_HH; i += gs) hbase[i]                    = __float2half_rn(Wh0[i]);
    if (wflags & 2) for (int i = gid; i < N_HH; i += gs) hbase[(size_t)N_HH + i]     = __float2half_rn(Wh1[i]);
    if (wflags & 4) for (int i = gid; i < N_HH; i += gs) hbase[2*(size_t)N_HH + i]   = __float2half_rn(Wi1[i]);
    if (wflags & 8) for (int i = gid; i < N_I0; i += gs) hbase[3*(size_t)N_HH + i]   = __float2half_rn(Wi0[i]);

    if (is_attn){
      // pmT[a][il] = mem[ab, ai0+il, :] . W_mem[a,:] + attn_b[a]
      float pacc[16];
      #pragma unroll
      for (int j=0;j<16;++j) pacc[j] = 0.f;
      for (int dc=0; dc<4; ++dc){
        for (int idx = tid; idx < 8192; idx += NT){
          int r = idx >> 7, d = idx & 127;
          sm[r*129 + d] = memory[(size_t)((ab<<9)+ai0+r)*DINz + (dc<<7) + d];
        }
        __syncthreads();
        #pragma unroll
        for (int j=0;j<16;++j){
          int a = (ag<<4) + j;
          const float* wr = W_mem + (size_t)a*DINz + (dc<<7);
          const float* mr = &sm[il*129];
          float acc = 0.f;
          for (int d=0; d<128; d+=4){
            acc = fmaf(mr[d  ], wr[d  ], acc);
            acc = fmaf(mr[d+1], wr[d+1], acc);
            acc = fmaf(mr[d+2], wr[d+2], acc);
            acc = fmaf(mr[d+3], wr[d+3], acc);
          }
          pacc[j] += acc;
        }
        __syncthreads();
      }
      #pragma unroll
      for (int j=0;j<16;++j){
        int a = (ag<<4) + j;
        pmT[((size_t)blk<<13) + (a<<6) + il] = pacc[j] + attn_b[a];
      }
      // persistent slabs: F = W_loc @ filters, v
      for (int idx = tid; idx < ATz*KFz; idx += NT){
        int a = idx / KFz, k = idx - a*KFz;
        float s2 = 0.f;
        #pragma unroll
        for (int c2=0;c2<LOCz;++c2) s2 = fmaf(W_loc[(a<<5)+c2], loc_f[c2*KFz+k], s2);
        sm[SMA_F + idx] = s2;
      }
      if (tid < 128) sm[SMA_V + tid] = attn_v[tid];
      __syncthreads();
    }

    // prenet for all (t,b) pairs; scratch in GEMM LDS area
    const int th = tid >> 8, t2 = tid & 255, base = th << 9;
    for (int it=0; it<3; ++it){
      int pp = (blk<<1) + th + (it<<9);
      bool act = pp < 1200;
      if (act && t2 < ODz){
        int tt = pp >> 3, bb = pp & 7;
        sm[base + t2] = (tt==0) ? 0.f : targets[((size_t)bb*TDz + (tt-1))*ODz + t2];
      }
      __syncthreads();
      if (act){
        float a1 = pre_b1[t2];
        for (int k=0;k<ODz;++k) a1 = fmaf(pre_W1[t2*ODz+k], sm[base+k], a1);
        sm[base + 128 + t2] = fmaxf(a1, 0.f);
      }
      __syncthreads();
      if (act){
        float a2 = pre_b2[t2];
        for (int k=0;k<PREz;++k) a2 = fmaf(pre_W2[(t2<<8)+k], sm[base+128+k], a2);
        Pw[((size_t)pp<<8) + t2] = fmaxf(a2, 0.f);
      }
      __syncthreads();
    }
  }
  grid_barrier_heavy(bar);

  // ------------------------------ MAIN LOOP (3 phases) ---------------------
  for (int t = 0; t < TDz; ++t){
    const int cur = t & 1, prv = cur ^ 1;

    // ---- P1: attention u + partial attc (0-63, then gh1 tile) |
    //          gh0 (64-191) | gh1 (192-255) ------------------------------
    if (is_attn){
      if (tid < 94){
        int gi = ai0 - 15 + tid;
        sm[SMA_CW + tid] = (gi >= 0 && gi < TE) ? ldg_sc1(&cum[(ab<<9)+gi]) : 0.f;
      }
      if (tid < 128) sm[SMA_Q + tid] = ldg_sc1(&qw[(tid<<3) + ab]);
      __syncthreads();
      float part = 0.f;
      #pragma unroll
      for (int j=0;j<16;++j){
        int a = (ag<<4) + j;
        const float* fb = &sm[SMA_F + a*KFz];
        float conv = 0.f;
        #pragma unroll
        for (int k=0;k<KFz;++k) conv = fmaf(fb[k], sm[SMA_CW + il + k], conv);
        float pv = pmT[((size_t)blk<<13) + (a<<6) + il];
        part = fmaf(sm[SMA_V + a], ftanh_(pv + sm[SMA_Q + a] + conv), part);
      }
      sm[SMA_PART + (il<<3) + ag] = part;
      __syncthreads();
      if (tid < 64){
        float e = 0.f;
        #pragma unroll
        for (int k=0;k<8;++k) e += sm[SMA_PART + (tid<<3) + k];
        int gi = ai0 + tid;
        float uu = (gi < mlen[ab]) ? __expf(e) : 0.f;
        stg_sc1(&uw[(ab<<9)+gi], uu);
        sm[SMA_U + tid] = uu;
      }
      __syncthreads();
      if (tid == 0){
        float ssum = 0.f;
        #pragma unroll
        for (int k=0;k<64;++k) ssum += sm[SMA_U + k];
        atomicAdd(&Sw[(cur<<3)+ab], ssum);
      }
      // partial att_c: thread d accumulates 64 positions, atomic into attc
      {
        float acc = 0.f;
        const float* mrow = memory + (size_t)((ab<<9)+ai0)*DINz + tid;
        #pragma unroll 4
        for (int i=0;i<64;++i)
          acc = fmaf(sm[SMA_U + i], mrow[(size_t)i*DINz], acc);
        atomicAdd(&attc[(cur<<12) + (ab<<9) + tid], acc);
      }
      // then one gh1 tile
      {
        float dot = (wflags & 2)
          ? gemm32x8<true >(sm, hWh1, 0, 0, blk<<5, DRz, 4, 0, h1, nullptr, nullptr, nullptr)
          : gemm32x8<false>(sm, Wh1,  0, 0, blk<<5, DRz, 4, 0, h1, nullptr, nullptr, nullptr);
        if (tid < 256) stg_sc1(&gh1[(blk<<8) + tid], dot);
      }
    } else if (blk < 192){
      int tile = blk - 64;
      float dot = (wflags & 1)
        ? gemm32x8<true >(sm, hWh0, 0, 0, tile<<5, DRz, 4, 0, h0, nullptr, nullptr, nullptr)
        : gemm32x8<false>(sm, Wh0,  0, 0, tile<<5, DRz, 4, 0, h0, nullptr, nullptr, nullptr);
      if (tid < 256) stg_sc1(&gh0[(tile<<8) + tid], dot);
    } else {
      int tile = blk - 128;   // gh1 tiles 64..127
      float dot = (wflags & 2)
        ? gemm32x8<true >(sm, hWh1, 0, 0, tile<<5, DRz, 4, 0, h1, nullptr, nullptr, nullptr)
        : gemm32x8<false>(sm, Wh1,  0, 0, tile<<5, DRz, 4, 0, h1, nullptr, nullptr, nullptr);
      if (tid < 256) stg_sc1(&gh1[(tile<<8) + tid], dot);
    }
    grid_barrier(bar);

    // ---- P2: attw/cum (0-7) | outstop t-1 (8-88) | LSTM0 (128-255) -------
    if (blk < 8){
      int b = blk;
      float Sv = __hip_atomic_load(&Sw[(cur<<3)+b], __ATOMIC_RELAXED, AG);
      float inv = 1.f / Sv;
      if (tid == 0) stg_sc1(&iSw[(cur<<3)+b], inv);
      for (int i = tid; i < TE; i += NT){
        float u = ldg_sc1(&uw[(b<<9)+i]);
        float w = u * inv;
        d_out[97200 + ((size_t)b*TDz + t)*TE + i] = w;
        stg_sc1(&cum[(b<<9)+i], ldg_sc1(&cum[(b<<9)+i]) + w);
      }
    } else if (blk < 89){
      if (t > 0)
        outstop_wave((blk-8)*8 + (tid>>6), t-1, prv,
                     feat_W, stop_W, stop_b, h1, attc, iSw, d_out);
    } else if (blk >= 128){
      int u0 = (blk - 128) << 3;
      float dot = (wflags & 8)
        ? gemm32x8<true >(sm, hWi0, 1, u0, 0, 768, 3, 1, nullptr,
                          attc + (cur<<12), Sw + (cur<<3), Pw + ((size_t)t<<11))
        : gemm32x8<false>(sm, Wi0,  1, u0, 0, 768, 3, 1, nullptr,
                          attc + (cur<<12), Sw + (cur<<3), Pw + ((size_t)t<<11));
      lstm_epilogue(sm, dot, bl0, gh0, h0, c0, u0);
    }
    grid_barrier(bar);

    // ---- P3: W_q (64-67) | zero attc[prv],S[prv] (68) | LSTM1 (128-255) --
    if (blk >= 64 && blk < 68){
      int rt = blk - 64;
      float dot = gemm32x8<false>(sm, W_q, 0, 0, rt<<5, DRz, 4,
                                  0, h0, nullptr, nullptr, nullptr);
      if (tid < 256) stg_sc1(&qw[(rt<<8) + tid], dot);
    } else if (blk == 68){
      for (int i = tid; i < 4096; i += NT) stg_sc1(&attc[(prv<<12) + i], 0.f);
      if (tid < 8) stg_sc1(&Sw[(prv<<3)+tid], 0.f);
    } else if (blk >= 128){
      int u0 = (blk - 128) << 3;
      float dot = (wflags & 4)
        ? gemm32x8<true >(sm, hWi1, 1, u0, 0, DRz, 4, 0, h0, nullptr, nullptr, nullptr)
        : gemm32x8<false>(sm, Wi1,  1, u0, 0, DRz, 4, 0, h0, nullptr, nullptr, nullptr);
      lstm_epilogue(sm, dot, bl1, gh1, h1, c1, u0);
    }
    grid_barrier(bar);
  }

  // final out/stop for t = 149 (parity 1)
  if (blk >= 8 && blk < 89)
    outstop_wave((blk-8)*8 + (tid>>6), TDz-1, 1,
                 feat_W, stop_W, stop_b, h1, attc, iSw, d_out);
}

extern "C" void kernel_launch(void* const* d_in, const int* in_sizes, int n_in,
                              void* d_out, int out_size, void* d_ws, size_t ws_size,
                              hipStream_t stream)
{
  (void)in_sizes; (void)n_in; (void)out_size;
  // per-matrix fp16 fit mask, priority Wh0 | Wh1 | Wi1 | Wi0 (packed in order)
  size_t base_b = (size_t)OF_F16 * 4;
  size_t avail = (ws_size > base_b) ? ws_size - base_b : 0;
  int wflags = 0;
  size_t need = 2*(size_t)N_HH;            if (need <= avail) wflags |= 1;  // Wh0
  need += 2*(size_t)N_HH;                  if (need <= avail) wflags |= 2;  // Wh1
  need += 2*(size_t)N_HH;                  if (need <= avail) wflags |= 4;  // Wi1
  need += 2*(size_t)N_I0;                  if (need <= avail) wflags |= 8;  // Wi0
  (void)hipMemsetAsync((char*)d_ws + (size_t)OF_BAR*4, 0, 2560, stream);
  dec_kernel<<<dim3(NB), dim3(NT), 0, stream>>>(
    (const float*)d_in[0],  (const int*)d_in[1],   (const float*)d_in[2],
    (const float*)d_in[3],  (const float*)d_in[4],  (const float*)d_in[5],
    (const float*)d_in[6],  (const float*)d_in[7],  (const float*)d_in[8],
    (const float*)d_in[9],  (const float*)d_in[10], (const float*)d_in[11], (const float*)d_in[12],
    (const float*)d_in[13], (const float*)d_in[14], (const float*)d_in[15],
    (const float*)d_in[16], (const float*)d_in[17], (const float*)d_in[18],
    (const float*)d_in[19], (const float*)d_in[20], (const float*)d_in[21],
    (float*)d_out, (float*)d_ws, wflags);
}

// Round 10
// 8345.310 us; speedup vs baseline: 5.6687x; 1.0938x over previous
//
#include <hip/hip_runtime.h>
#include <hip/hip_fp16.h>
#include <cstdint>
#include <cstddef>

// ---------------------------------------------------------------------------
// Tacotron2-style decoder, persistent kernel. 256 blocks x 512 threads.
// 3 phases/step, ~1 GEMM per block per phase. fp16 weights in ws (per-matrix
// fit mask). Full-depth register prefetch in the GEMM. Replicated-epoch
// barrier. Cross-block state via sc1 (LLC).
// ---------------------------------------------------------------------------

#define NB 256
#define NT 512

#define Bz   8
#define TE   512
#define DINz 512
#define TDz  150
#define ODz  80
#define DRz  1024
#define PREz 256
#define ATz  128
#define LOCz 32
#define KFz  31

// workspace offsets (floats)
#define OF_P    0            // prenet [1200][256]
#define OF_PM   307200       // pmT per attention block [64][128a][64il]
#define OF_Q    831488       // q [128a][8b]
#define OF_U    832512       // u [8][512]
#define OF_CUM  836608       // att_cum [8][512]
#define OF_ATTC 840704       // unnormalized att_c [2][8][512] (atomic-accum)
#define OF_S    848896       // S [2][8]
#define OF_INVS 848912       // 1/S [2][8]
#define OF_H0   848928
#define OF_C0   857120
#define OF_H1   865312
#define OF_C1   873504
#define OF_GH0  881696       // gh0 [4096][8]
#define OF_GH1  914464       // gh1 [4096][8]
#define OF_BAR  947232       // 1536 ints: leaves[16*32] | root@512 | epochs@1024+i*32
#define OF_F16  948768       // fp16 region (halves): Wh0|Wh1|Wi1|Wi0|Wq
#define N_I0    3145728      // 4096*768
#define N_HH    4194304      // 4096*1024
#define N_Q     131072       // 128*1024

// shared memory (floats)
#define SM_WT 0       // W tile: fp32 32x256 (8192f) OR fp16 32x256 (first 4096f)
#define SM_XT 8192    // X tile 8x256
#define SM_G  10240   // gate exchange 256
// persistent attention slabs (blk<64), above all GEMM areas
#define SMA_F    10496  // F[a*31+k] (3968)
#define SMA_V    14464  // v[128]
#define SMA_CW   14592  // cum window 96
#define SMA_Q    14688  // q[128]
#define SMA_PART 14816  // partials [64][8]
#define SMA_U    15328  // u stage 64
#define SM_TOT   15392  // 61568 B

#define AG __HIP_MEMORY_SCOPE_AGENT

__device__ __forceinline__ float ldg_sc1(const float* p){
  return __hip_atomic_load(p, __ATOMIC_RELAXED, AG);
}
__device__ __forceinline__ void stg_sc1(float* p, float v){
  __hip_atomic_store(p, v, __ATOMIC_RELAXED, AG);
}
__device__ __forceinline__ float4 ldg4_sc1(const float* p){
  float4 r; r.x=ldg_sc1(p); r.y=ldg_sc1(p+1); r.z=ldg_sc1(p+2); r.w=ldg_sc1(p+3);
  return r;
}
__device__ __forceinline__ float fsig_(float x){ return 1.f/(1.f + __expf(-x)); }
__device__ __forceinline__ float ftanh_(float x){
  x = fminf(10.f, fmaxf(-10.f, x));
  float e = __expf(2.f*x);
  return (e - 1.f) / (e + 1.f);
}

// light barrier: replicated epochs (16 lines), no cache maintenance
__device__ __forceinline__ void grid_barrier(int* bar){
  asm volatile("s_waitcnt vmcnt(0) lgkmcnt(0)" ::: "memory");
  __syncthreads();
  if (threadIdx.x == 0){
    const int lf = blockIdx.x >> 4;
    int* leaf  = bar + (lf << 5);
    int* root  = bar + 512;
    int* ep    = bar + 1024 + (lf << 5);
    int g = __hip_atomic_load(ep, __ATOMIC_RELAXED, AG);
    int lo = __hip_atomic_fetch_add(leaf, 1, __ATOMIC_RELAXED, AG);
    if ((lo & 15) == 15){
      int ro = __hip_atomic_fetch_add(root, 1, __ATOMIC_RELAXED, AG);
      if ((ro & 15) == 15){
        #pragma unroll
        for (int i=0;i<16;++i)
          __hip_atomic_store(bar + 1024 + (i<<5), g + 1, __ATOMIC_RELAXED, AG);
      }
    }
    while (__hip_atomic_load(ep, __ATOMIC_RELAXED, AG) == g)
      __builtin_amdgcn_s_sleep(1);
  }
  __syncthreads();
}
// heavy barrier (after init only): flush cached init writes, invalidate
__device__ __forceinline__ void grid_barrier_heavy(int* bar){
  asm volatile("s_waitcnt vmcnt(0) lgkmcnt(0)" ::: "memory");
  __syncthreads();
  if (threadIdx.x == 0){
    __builtin_amdgcn_fence(__ATOMIC_RELEASE, "agent");
    const int lf = blockIdx.x >> 4;
    int* leaf  = bar + (lf << 5);
    int* root  = bar + 512;
    int* ep    = bar + 1024 + (lf << 5);
    int g = __hip_atomic_load(ep, __ATOMIC_RELAXED, AG);
    int lo = __hip_atomic_fetch_add(leaf, 1, __ATOMIC_RELAXED, AG);
    if ((lo & 15) == 15){
      int ro = __hip_atomic_fetch_add(root, 1, __ATOMIC_RELAXED, AG);
      if ((ro & 15) == 15){
        #pragma unroll
        for (int i=0;i<16;++i)
          __hip_atomic_store(bar + 1024 + (i<<5), g + 1, __ATOMIC_RELAXED, AG);
      }
    }
    while (__hip_atomic_load(ep, __ATOMIC_RELAXED, AG) == g)
      __builtin_amdgcn_s_sleep(1);
    __builtin_amdgcn_fence(__ATOMIC_ACQUIRE, "agent");
  }
  __syncthreads();
}

// GEMM tile: out[row 0..31][b 0..7] = sum_k W[maprow(row)][k] * X[b][k]
// F16 path: ALL chunks' W+X loads issued upfront (full-depth prefetch).
// xmode==1: X = [attc*(1/S) | prenet]; S_cur read directly.
template<bool F16>
__device__ float gemm32x8(
    float* sm, const void* Wv,
    int gatemap, int u0, int rowbase, int K, int nch,
    int xmode, const float* __restrict__ xsrc,
    const float* __restrict__ attc_cur, const float* __restrict__ S_cur,
    const float* __restrict__ Pt)
{
  const int tid = threadIdx.x;
  const int s = tid & 31, pos = tid >> 5;
  __half* smW16 = (__half*)sm;
  float acc[2][8];
  #pragma unroll
  for (int i=0;i<2;++i){
    #pragma unroll
    for (int b=0;b<8;++b) acc[i][b] = 0.f;
  }
  const __half* p16[2]; int st16[2];
  const float* p32[4]; int st32[4];
  if (F16){
    const __half* W16 = (const __half*)Wv;
    #pragma unroll
    for (int it=0; it<2; ++it){
      int idx = tid + (it<<9);
      int r = idx >> 5, g = idx & 31;
      int grow = gatemap ? (((r>>3)<<10) + u0 + (r&7)) : (rowbase + r);
      p16[it] = W16 + (size_t)grow*K + (g<<3);
      st16[it] = (r<<8) + (g<<3);
    }
  } else {
    const float* W32 = (const float*)Wv;
    #pragma unroll
    for (int it=0; it<4; ++it){
      int idx4 = tid + (it<<9);
      int r = idx4 >> 6, col = (idx4 & 63) << 2;
      int grow = gatemap ? (((r>>3)<<10) + u0 + (r&7)) : (rowbase + r);
      p32[it] = W32 + (size_t)grow*K + col;
      st32[it] = SM_WT + (r<<8) + col;
    }
  }
  const int xb = tid >> 6, xcol = (tid & 63) << 2;
  float xsc = (xmode == 1) ? (1.f / ldg_sc1(S_cur + xb)) : 1.f;

  uint4 w16r[4][2]; float4 w32r[4]; float4 xreg[4];
  if (F16){
    #pragma unroll
    for (int ch=0; ch<4; ++ch) if (ch < nch){
      w16r[ch][0] = *(const uint4*)(p16[0] + (ch<<8));
      w16r[ch][1] = *(const uint4*)(p16[1] + (ch<<8));
    }
  } else {
    #pragma unroll
    for (int it=0;it<4;++it) w32r[it] = *(const float4*)(p32[it]);
  }
  #pragma unroll
  for (int ch=0; ch<4; ++ch) if (ch < nch){
    if (xmode == 0)      xreg[ch] = ldg4_sc1(xsrc + (size_t)xb*K + (ch<<8) + xcol);
    else if (ch < 2)     xreg[ch] = ldg4_sc1(attc_cur + (xb<<9) + (ch<<8) + xcol);
    else                 xreg[ch] = *(const float4*)(Pt + (xb<<8) + xcol);
  }

  for (int ch=0; ch<nch; ++ch){
    __syncthreads();
    if (F16){
      *(uint4*)&smW16[st16[0]] = w16r[ch][0];
      *(uint4*)&smW16[st16[1]] = w16r[ch][1];
    } else {
      #pragma unroll
      for (int it=0;it<4;++it) *(float4*)&sm[st32[it]] = w32r[it];
    }
    {
      float4 v = xreg[ch];
      if (xmode == 1 && ch < 2){ v.x*=xsc; v.y*=xsc; v.z*=xsc; v.w*=xsc; }
      *(float4*)&sm[SM_XT + (xb<<8) + xcol] = v;
    }
    __syncthreads();
    if (!F16 && ch+1 < nch){
      const int c1 = (ch+1) << 8;
      #pragma unroll
      for (int it=0;it<4;++it) w32r[it] = *(const float4*)(p32[it] + c1);
    }
    #pragma unroll
    for (int j=0;j<2;++j){
      const int k = (j<<7) + (s<<2);
      float4 xv[8];
      #pragma unroll
      for (int b=0;b<8;++b) xv[b] = *(const float4*)&sm[SM_XT + (b<<8) + k];
      #pragma unroll
      for (int i=0;i<2;++i){
        float4 wv;
        if (F16){
          uint2 w2 = *(const uint2*)&smW16[(((pos<<1)+i)<<8) + k];
          __half2 ha = *reinterpret_cast<const __half2*>(&w2.x);
          __half2 hb = *reinterpret_cast<const __half2*>(&w2.y);
          float2 fa = __half22float2(ha);
          float2 fb = __half22float2(hb);
          wv.x = fa.x; wv.y = fa.y; wv.z = fb.x; wv.w = fb.y;
        } else {
          wv = *(const float4*)&sm[SM_WT + (((pos<<1)+i)<<8) + k];
        }
        #pragma unroll
        for (int b=0;b<8;++b){
          acc[i][b] = fmaf(wv.x, xv[b].x, acc[i][b]);
          acc[i][b] = fmaf(wv.y, xv[b].y, acc[i][b]);
          acc[i][b] = fmaf(wv.z, xv[b].z, acc[i][b]);
          acc[i][b] = fmaf(wv.w, xv[b].w, acc[i][b]);
        }
      }
    }
  }
  __syncthreads();
  #pragma unroll
  for (int i=0;i<2;++i){
    #pragma unroll
    for (int b=0;b<8;++b){
      int ridx = ((((pos<<1)+i)<<3) | b);
      sm[ridx*33 + s] = acc[i][b];
    }
  }
  __syncthreads();
  float sum = 0.f;
  if (tid < 256){
    #pragma unroll
    for (int s2=0;s2<32;++s2) sum += sm[tid*33 + s2];
  }
  return sum;
}

__device__ void lstm_epilogue(float* sm, float dot,
                              const float* __restrict__ bias,
                              const float* __restrict__ gh,
                              float* __restrict__ h, float* __restrict__ c, int u0)
{
  const int tid = threadIdx.x;
  if (tid < 256){
    int row32 = tid >> 3, b = tid & 7;
    int gate = row32 >> 3, ul = row32 & 7;
    int grow = (gate<<10) + u0 + ul;
    sm[SM_G + tid] = dot + bias[grow] + ldg_sc1(&gh[(grow<<3) + b]);
  }
  __syncthreads();
  if (tid < 64){
    float gi = sm[SM_G + tid];
    float gf = sm[SM_G + 64 + tid];
    float gg = sm[SM_G + 128 + tid];
    float go = sm[SM_G + 192 + tid];
    int ul2 = tid >> 3, b2 = tid & 7;
    int hi = (b2<<10) + u0 + ul2;
    float co = c[hi];               // block-private: cached
    float ho = ldg_sc1(&h[hi]);     // shared: sc1
    float cn = fsig_(gf)*co + fsig_(gi)*ftanh_(gg);
    float hn = fsig_(go)*ftanh_(cn);
    c[hi] = 0.9f*cn + 0.1f*co;
    stg_sc1(&h[hi], 0.9f*hn + 0.1f*ho);
  }
}

// one output row per wave: rr = b*81 + r (r==80 -> stop)
__device__ void outstop_wave(int rr, int tp, int par,
    const float* __restrict__ feat_W, const float* __restrict__ stop_W,
    const float* __restrict__ stop_b, const float* __restrict__ h1,
    const float* __restrict__ attc, const float* __restrict__ iSw,
    float* __restrict__ d_out)
{
  if (rr >= 648) return;
  int b = rr / 81, r = rr - 81*b;
  int lane = threadIdx.x & 63;
  const float4* Wr = (const float4*)((r < 80) ? (feat_W + (size_t)r*1536) : stop_W);
  float inv = ldg_sc1(iSw + (par<<3) + b);
  float acc = 0.f, acc2 = 0.f;
  #pragma unroll
  for (int j=0;j<4;++j){
    int p = lane + (j<<6);
    float4 w = Wr[p], x = ldg4_sc1(h1 + (b<<10) + (p<<2));
    acc = fmaf(w.x,x.x, fmaf(w.y,x.y, fmaf(w.z,x.z, fmaf(w.w,x.w, acc))));
  }
  #pragma unroll
  for (int j=4;j<6;++j){
    int p = lane + (j<<6);
    float4 w = Wr[p], x = ldg4_sc1(attc + (par<<12) + (b<<9) + ((p-256)<<2));
    acc2 = fmaf(w.x,x.x, fmaf(w.y,x.y, fmaf(w.z,x.z, fmaf(w.w,x.w, acc2))));
  }
  acc += acc2 * inv;
  acc += __shfl_down(acc, 32, 64);
  acc += __shfl_down(acc, 16, 64);
  acc += __shfl_down(acc,  8, 64);
  acc += __shfl_down(acc,  4, 64);
  acc += __shfl_down(acc,  2, 64);
  acc += __shfl_down(acc,  1, 64);
  if (lane == 0){
    if (r < 80) d_out[((size_t)b*TDz + tp)*ODz + r] = acc;
    else        d_out[96000 + (size_t)b*TDz + tp] = acc + stop_b[0];
  }
}

extern "C" __global__ void __launch_bounds__(NT, 2) dec_kernel(
  const float* __restrict__ memory, const int* __restrict__ mlen, const float* __restrict__ targets,
  const float* __restrict__ W_mem, const float* __restrict__ W_q, const float* __restrict__ W_loc,
  const float* __restrict__ loc_f, const float* __restrict__ attn_v, const float* __restrict__ attn_b,
  const float* __restrict__ pre_W1, const float* __restrict__ pre_b1,
  const float* __restrict__ pre_W2, const float* __restrict__ pre_b2,
  const float* __restrict__ Wi0, const float* __restrict__ Wh0, const float* __restrict__ bl0,
  const float* __restrict__ Wi1, const float* __restrict__ Wh1, const float* __restrict__ bl1,
  const float* __restrict__ feat_W, const float* __restrict__ stop_W, const float* __restrict__ stop_b,
  float* __restrict__ d_out, float* __restrict__ ws, int wflags)
{
  __shared__ float sm[SM_TOT];
  const int blk = blockIdx.x, tid = threadIdx.x;

  float* Pw   = ws + OF_P;
  float* pmT  = ws + OF_PM;
  float* qw   = ws + OF_Q;
  float* uw   = ws + OF_U;
  float* cum  = ws + OF_CUM;
  float* attc = ws + OF_ATTC;
  float* Sw   = ws + OF_S;
  float* iSw  = ws + OF_INVS;
  float* h0 = ws + OF_H0; float* c0 = ws + OF_C0;
  float* h1 = ws + OF_H1; float* c1 = ws + OF_C1;
  float* gh0 = ws + OF_GH0; float* gh1 = ws + OF_GH1;
  int* bar = (int*)(ws + OF_BAR);
  __half* hbase = (__half*)(ws + OF_F16);     // Wh0|Wh1|Wi1|Wi0|Wq
  const __half* hWh0 = hbase;
  const __half* hWh1 = hbase + (size_t)N_HH;
  const __half* hWi1 = hbase + 2*(size_t)N_HH;
  const __half* hWi0 = hbase + 3*(size_t)N_HH;
  const __half* hWq  = hbase + 3*(size_t)N_HH + (size_t)N_I0;

  const bool is_attn = (blk < 64);
  const int ab  = blk >> 3;          // attention batch
  const int ai0 = (blk & 7) << 6;    // attention base position
  const int il  = tid & 63;          // position within slice
  const int ag  = tid >> 6;          // feature group (0..7)

  // ------------------------- INIT (every launch) ---------------------------
  {
    const int gs = NB*NT;
    int gid = blk*NT + tid;
    for (int i = gid; i < 98304; i += gs) h0[i] = 0.f;    // h0,c0,h1,c1,gh0,gh1
    for (int i = gid; i < 1024;  i += gs) qw[i]  = 0.f;
    for (int i = gid; i < 4096;  i += gs) cum[i] = 0.f;
    for (int i = gid; i < 8192;  i += gs) attc[i] = 0.f;
    if (gid < 32) Sw[gid] = 0.f;                          // S + invS

    if (wflags & 1)  for (int i = gid; i < N_HH; i += gs) hbase[i]                                = __float2half_rn(Wh0[i]);
    if (wflags & 2)  for (int i = gid; i < N_HH; i += gs) hbase[(size_t)N_HH + i]                 = __float2half_rn(Wh1[i]);
    if (wflags & 4)  for (int i = gid; i < N_HH; i += gs) hbase[2*(size_t)N_HH + i]               = __float2half_rn(Wi1[i]);
    if (wflags & 8)  for (int i = gid; i < N_I0; i += gs) hbase[3*(size_t)N_HH + i]               = __float2half_rn(Wi0[i]);
    if (wflags & 16) for (int i = gid; i < N_Q;  i += gs) hbase[3*(size_t)N_HH + (size_t)N_I0 + i]= __float2half_rn(W_q[i]);

    if (is_attn){
      // pmT[a][il] = mem[ab, ai0+il, :] . W_mem[a,:] + attn_b[a]
      float pacc[16];
      #pragma unroll
      for (int j=0;j<16;++j) pacc[j] = 0.f;
      for (int dc=0; dc<4; ++dc){
        for (int idx = tid; idx < 8192; idx += NT){
          int r = idx >> 7, d = idx & 127;
          sm[r*129 + d] = memory[(size_t)((ab<<9)+ai0+r)*DINz + (dc<<7) + d];
        }
        __syncthreads();
        #pragma unroll
        for (int j=0;j<16;++j){
          int a = (ag<<4) + j;
          const float* wr = W_mem + (size_t)a*DINz + (dc<<7);
          const float* mr = &sm[il*129];
          float acc = 0.f;
          for (int d=0; d<128; d+=4){
            acc = fmaf(mr[d  ], wr[d  ], acc);
            acc = fmaf(mr[d+1], wr[d+1], acc);
            acc = fmaf(mr[d+2], wr[d+2], acc);
            acc = fmaf(mr[d+3], wr[d+3], acc);
          }
          pacc[j] += acc;
        }
        __syncthreads();
      }
      #pragma unroll
      for (int j=0;j<16;++j){
        int a = (ag<<4) + j;
        pmT[((size_t)blk<<13) + (a<<6) + il] = pacc[j] + attn_b[a];
      }
      // persistent slabs: F = W_loc @ filters, v
      for (int idx = tid; idx < ATz*KFz; idx += NT){
        int a = idx / KFz, k = idx - a*KFz;
        float s2 = 0.f;
        #pragma unroll
        for (int c2=0;c2<LOCz;++c2) s2 = fmaf(W_loc[(a<<5)+c2], loc_f[c2*KFz+k], s2);
        sm[SMA_F + idx] = s2;
      }
      if (tid < 128) sm[SMA_V + tid] = attn_v[tid];
      __syncthreads();
    }

    // prenet for all (t,b) pairs; scratch in GEMM LDS area
    const int th = tid >> 8, t2 = tid & 255, base = th << 9;
    for (int it=0; it<3; ++it){
      int pp = (blk<<1) + th + (it<<9);
      bool act = pp < 1200;
      if (act && t2 < ODz){
        int tt = pp >> 3, bb = pp & 7;
        sm[base + t2] = (tt==0) ? 0.f : targets[((size_t)bb*TDz + (tt-1))*ODz + t2];
      }
      __syncthreads();
      if (act){
        float a1 = pre_b1[t2];
        for (int k=0;k<ODz;++k) a1 = fmaf(pre_W1[t2*ODz+k], sm[base+k], a1);
        sm[base + 128 + t2] = fmaxf(a1, 0.f);
      }
      __syncthreads();
      if (act){
        float a2 = pre_b2[t2];
        for (int k=0;k<PREz;++k) a2 = fmaf(pre_W2[(t2<<8)+k], sm[base+128+k], a2);
        Pw[((size_t)pp<<8) + t2] = fmaxf(a2, 0.f);
      }
      __syncthreads();
    }
  }
  grid_barrier_heavy(bar);

  // ------------------------------ MAIN LOOP (3 phases) ---------------------
  for (int t = 0; t < TDz; ++t){
    const int cur = t & 1, prv = cur ^ 1;

    // ---- P1: attention (0-63) | gh1 tiles 0-127 (64-191) |
    //          gh0 tiles 124-127 (192-195) --------------------------------
    if (is_attn){
      if (tid < 94){
        int gi = ai0 - 15 + tid;
        sm[SMA_CW + tid] = (gi >= 0 && gi < TE) ? ldg_sc1(&cum[(ab<<9)+gi]) : 0.f;
      }
      if (tid < 128) sm[SMA_Q + tid] = ldg_sc1(&qw[(tid<<3) + ab]);
      __syncthreads();
      float part = 0.f;
      #pragma unroll
      for (int j=0;j<16;++j){
        int a = (ag<<4) + j;
        const float* fb = &sm[SMA_F + a*KFz];
        float conv = 0.f;
        #pragma unroll
        for (int k=0;k<KFz;++k) conv = fmaf(fb[k], sm[SMA_CW + il + k], conv);
        float pv = pmT[((size_t)blk<<13) + (a<<6) + il];
        part = fmaf(sm[SMA_V + a], ftanh_(pv + sm[SMA_Q + a] + conv), part);
      }
      sm[SMA_PART + (il<<3) + ag] = part;
      __syncthreads();
      if (tid < 64){
        float e = 0.f;
        #pragma unroll
        for (int k=0;k<8;++k) e += sm[SMA_PART + (tid<<3) + k];
        int gi = ai0 + tid;
        float uu = (gi < mlen[ab]) ? __expf(e) : 0.f;
        stg_sc1(&uw[(ab<<9)+gi], uu);
        sm[SMA_U + tid] = uu;
      }
      __syncthreads();
      if (tid == 0){
        float ssum = 0.f;
        #pragma unroll
        for (int k=0;k<64;++k) ssum += sm[SMA_U + k];
        atomicAdd(&Sw[(cur<<3)+ab], ssum);
      }
      // partial att_c: thread d accumulates 64 positions, atomic into attc
      {
        float acc = 0.f;
        const float* mrow = memory + (size_t)((ab<<9)+ai0)*DINz + tid;
        #pragma unroll 4
        for (int i=0;i<64;++i)
          acc = fmaf(sm[SMA_U + i], mrow[(size_t)i*DINz], acc);
        atomicAdd(&attc[(cur<<12) + (ab<<9) + tid], acc);
      }
    } else if (blk < 192){
      int tile = blk - 64;
      float dot = (wflags & 2)
        ? gemm32x8<true >(sm, hWh1, 0, 0, tile<<5, DRz, 4, 0, h1, nullptr, nullptr, nullptr)
        : gemm32x8<false>(sm, Wh1,  0, 0, tile<<5, DRz, 4, 0, h1, nullptr, nullptr, nullptr);
      if (tid < 256) stg_sc1(&gh1[(tile<<8) + tid], dot);
    } else if (blk < 196){
      int tile = 124 + (blk - 192);
      float dot = (wflags & 1)
        ? gemm32x8<true >(sm, hWh0, 0, 0, tile<<5, DRz, 4, 0, h0, nullptr, nullptr, nullptr)
        : gemm32x8<false>(sm, Wh0,  0, 0, tile<<5, DRz, 4, 0, h0, nullptr, nullptr, nullptr);
      if (tid < 256) stg_sc1(&gh0[(tile<<8) + tid], dot);
    }
    grid_barrier(bar);

    // ---- P2: attw/cum (0-7) | outstop t-1 (8-88) | LSTM0 (128-255) -------
    if (blk < 8){
      int b = blk;
      float Sv = __hip_atomic_load(&Sw[(cur<<3)+b], __ATOMIC_RELAXED, AG);
      float inv = 1.f / Sv;
      if (tid == 0) stg_sc1(&iSw[(cur<<3)+b], inv);
      for (int i = tid; i < TE; i += NT){
        float u = ldg_sc1(&uw[(b<<9)+i]);
        float w = u * inv;
        d_out[97200 + ((size_t)b*TDz + t)*TE + i] = w;
        stg_sc1(&cum[(b<<9)+i], ldg_sc1(&cum[(b<<9)+i]) + w);
      }
    } else if (blk < 89){
      if (t > 0)
        outstop_wave((blk-8)*8 + (tid>>6), t-1, prv,
                     feat_W, stop_W, stop_b, h1, attc, iSw, d_out);
    } else if (blk >= 128){
      int u0 = (blk - 128) << 3;
      float dot = (wflags & 8)
        ? gemm32x8<true >(sm, hWi0, 1, u0, 0, 768, 3, 1, nullptr,
                          attc + (cur<<12), Sw + (cur<<3), Pw + ((size_t)t<<11))
        : gemm32x8<false>(sm, Wi0,  1, u0, 0, 768, 3, 1, nullptr,
                          attc + (cur<<12), Sw + (cur<<3), Pw + ((size_t)t<<11));
      lstm_epilogue(sm, dot, bl0, gh0, h0, c0, u0);
    }
    grid_barrier(bar);

    // ---- P3: gh0 tiles 0-123 (0-123) | W_q + zero duties (124-127) |
    //          LSTM1 (128-255) --------------------------------------------
    if (blk < 124){
      float dot = (wflags & 1)
        ? gemm32x8<true >(sm, hWh0, 0, 0, blk<<5, DRz, 4, 0, h0, nullptr, nullptr, nullptr)
        : gemm32x8<false>(sm, Wh0,  0, 0, blk<<5, DRz, 4, 0, h0, nullptr, nullptr, nullptr);
      if (tid < 256) stg_sc1(&gh0[(blk<<8) + tid], dot);
    } else if (blk < 128){
      int rt = blk - 124;
      float dot = (wflags & 16)
        ? gemm32x8<true >(sm, hWq, 0, 0, rt<<5, DRz, 4, 0, h0, nullptr, nullptr, nullptr)
        : gemm32x8<false>(sm, W_q, 0, 0, rt<<5, DRz, 4, 0, h0, nullptr, nullptr, nullptr);
      if (tid < 256) stg_sc1(&qw[(rt<<8) + tid], dot);
      // zero duties: quarter of attc[prv] each; block 124 zeroes S[prv]
      int zbase = (prv<<12) + (rt<<10);
      for (int i = tid; i < 1024; i += NT) stg_sc1(&attc[zbase + i], 0.f);
      if (rt == 0 && tid < 8) stg_sc1(&Sw[(prv<<3)+tid], 0.f);
    } else {
      int u0 = (blk - 128) << 3;
      float dot = (wflags & 4)
        ? gemm32x8<true >(sm, hWi1, 1, u0, 0, DRz, 4, 0, h0, nullptr, nullptr, nullptr)
        : gemm32x8<false>(sm, Wi1,  1, u0, 0, DRz, 4, 0, h0, nullptr, nullptr, nullptr);
      lstm_epilogue(sm, dot, bl1, gh1, h1, c1, u0);
    }
    grid_barrier(bar);
  }

  // final out/stop for t = 149 (parity 1)
  if (blk >= 8 && blk < 89)
    outstop_wave((blk-8)*8 + (tid>>6), TDz-1, 1,
                 feat_W, stop_W, stop_b, h1, attc, iSw, d_out);
}

extern "C" void kernel_launch(void* const* d_in, const int* in_sizes, int n_in,
                              void* d_out, int out_size, void* d_ws, size_t ws_size,
                              hipStream_t stream)
{
  (void)in_sizes; (void)n_in; (void)out_size;
  // per-matrix fp16 fit mask, priority Wh0 | Wh1 | Wi1 | Wi0 | Wq
  size_t base_b = (size_t)OF_F16 * 4;
  size_t avail = (ws_size > base_b) ? ws_size - base_b : 0;
  int wflags = 0;
  size_t need = 2*(size_t)N_HH;            if (need <= avail) wflags |= 1;   // Wh0
  need += 2*(size_t)N_HH;                  if (need <= avail) wflags |= 2;   // Wh1
  need += 2*(size_t)N_HH;                  if (need <= avail) wflags |= 4;   // Wi1
  need += 2*(size_t)N_I0;                  if (need <= avail) wflags |= 8;   // Wi0
  need += 2*(size_t)N_Q;                   if (need <= avail) wflags |= 16;  // Wq
  (void)hipMemsetAsync((char*)d_ws + (size_t)OF_BAR*4, 0, 6144, stream);
  dec_kernel<<<dim3(NB), dim3(NT), 0, stream>>>(
    (const float*)d_in[0],  (const int*)d_in[1],   (const float*)d_in[2],
    (const float*)d_in[3],  (const float*)d_in[4],  (const float*)d_in[5],
    (const float*)d_in[6],  (const float*)d_in[7],  (const float*)d_in[8],
    (const float*)d_in[9],  (const float*)d_in[10], (const float*)d_in[11], (const float*)d_in[12],
    (const float*)d_in[13], (const float*)d_in[14], (const float*)d_in[15],
    (const float*)d_in[16], (const float*)d_in[17], (const float*)d_in[18],
    (const float*)d_in[19], (const float*)d_in[20], (const float*)d_in[21],
    (float*)d_out, (float*)d_ws, wflags);
}